// Round 1
// baseline (3691.577 us; speedup 1.0000x reference)
//
#include <hip/hip_runtime.h>
#include <math.h>

#define BT      4096
#define T_SEQ   2048
#define E_DIM   1024
#define V_DIM   2048
#define H_HEADS 8
#define DK      128
#define DV      256
#define QKV_LD  4096

__device__ __forceinline__ void decay_params(int h, float& ld, float& gamma) {
    const float s0 = -3.4657359027997265f;  // ln(1/32)
    const float e0 = -6.2383246250395092f;  // ln(1/512)
    float lin = s0 + (e0 - s0) * ((float)h * (1.0f / 7.0f));
    gamma = 1.0f - expf(lin);
    ld = logf(gamma);
}

// ---------------------------------------------------------------------------
// Generic tiled fp32 GEMM: C(M,N) = A(M,K)@B(K,N) + bias, row-major, lda/ldb/ldc
// 128x128 tile, 256 threads, 8x8 microtile (split 4+4 at stride 64), BK=8.
// EPI 0: C = acc + bias
// EPI 1: x = acc + bias; C = silu(x) * extra[m*lde+n]
// ---------------------------------------------------------------------------
template<int EPI>
__global__ __launch_bounds__(256)
void gemm_kernel(const float* __restrict__ A, int lda,
                 const float* __restrict__ Bm, int ldb,
                 const float* __restrict__ bias,
                 float* __restrict__ C, int ldc,
                 const float* __restrict__ extra, int lde,
                 int M, int N, int K)
{
    __shared__ float As[8][128];
    __shared__ float Bs[8][128];
    const int tid = threadIdx.x;
    const int n0 = blockIdx.x * 128;
    const int m0 = blockIdx.y * 128;

    const int arow = tid >> 1, aseg = tid & 1;
    const int brow = tid >> 5, bc4  = tid & 31;

    const float* Aptr = A + (size_t)(m0 + arow) * lda + aseg * 4;
    const float* Bptr = Bm + (size_t)brow * ldb + n0 + bc4 * 4;

    float4 a4 = *(const float4*)Aptr;
    float4 b4 = *(const float4*)Bptr;

    float acc[8][8];
    #pragma unroll
    for (int i = 0; i < 8; ++i)
        #pragma unroll
        for (int j = 0; j < 8; ++j) acc[i][j] = 0.0f;

    const int tx = tid & 15, ty = tid >> 4;

    const int nk = K >> 3;
    for (int kt = 0; kt < nk; ++kt) {
        As[aseg * 4 + 0][arow] = a4.x;
        As[aseg * 4 + 1][arow] = a4.y;
        As[aseg * 4 + 2][arow] = a4.z;
        As[aseg * 4 + 3][arow] = a4.w;
        *(float4*)&Bs[brow][bc4 * 4] = b4;
        __syncthreads();
        if (kt + 1 < nk) {
            a4 = *(const float4*)(Aptr + (kt + 1) * 8);
            b4 = *(const float4*)(Bptr + (size_t)(kt + 1) * 8 * ldb);
        }
        #pragma unroll
        for (int kk = 0; kk < 8; ++kk) {
            float ar[8], br[8];
            *(float4*)&ar[0] = *(const float4*)&As[kk][ty * 4];
            *(float4*)&ar[4] = *(const float4*)&As[kk][64 + ty * 4];
            *(float4*)&br[0] = *(const float4*)&Bs[kk][tx * 4];
            *(float4*)&br[4] = *(const float4*)&Bs[kk][64 + tx * 4];
            #pragma unroll
            for (int i = 0; i < 8; ++i)
                #pragma unroll
                for (int j = 0; j < 8; ++j)
                    acc[i][j] = fmaf(ar[i], br[j], acc[i][j]);
        }
        __syncthreads();
    }

    #pragma unroll
    for (int ii = 0; ii < 8; ++ii) {
        int m = m0 + ((ii < 4) ? (ty * 4 + ii) : (64 + ty * 4 + ii - 4));
        #pragma unroll
        for (int jh = 0; jh < 2; ++jh) {
            int n = n0 + jh * 64 + tx * 4;
            float4 bb = *(const float4*)&bias[n];
            const float* av = &acc[ii][jh * 4];
            float4 res;
            res.x = av[0] + bb.x;
            res.y = av[1] + bb.y;
            res.z = av[2] + bb.z;
            res.w = av[3] + bb.w;
            if (EPI == 1) {
                float4 ex = *(const float4*)&extra[(size_t)m * lde + n];
                res.x = res.x / (1.0f + expf(-res.x)) * ex.x;
                res.y = res.y / (1.0f + expf(-res.y)) * ex.y;
                res.z = res.z / (1.0f + expf(-res.z)) * ex.z;
                res.w = res.w / (1.0f + expf(-res.w)) * ex.w;
            }
            *(float4*)&C[(size_t)m * ldc + n] = res;
        }
    }
}

// ---------------------------------------------------------------------------
// xPos rotary, in place on qkv buffer. q: cols [0,1024) downscale=false;
// k: cols [1024,2048) downscale=true.
// ---------------------------------------------------------------------------
__global__ __launch_bounds__(256)
void xpos_kernel(float* __restrict__ qkv)
{
    int p = blockIdx.x * 256 + threadIdx.x;   // 0..1023 pair slots (512 q, 512 k)
    int row = blockIdx.y;                     // 0..4095
    int t = row & (T_SEQ - 1);
    bool isK = p >= 512;
    int ip = isK ? (p - 512) : p;             // pair index 0..511
    int col = (isK ? E_DIM : 0) + 2 * ip;

    float sv = (2.0f * (float)ip + 409.6f) * (1.0f / 1433.6f);
    float sc = powf(sv, (float)t * (1.0f / 512.0f));
    if (isK) sc = 1.0f / sc;
    float invf = powf(10000.0f, -(float)ip * (1.0f / 512.0f));
    float ang = (float)t * invf;
    float sn, cs;
    sincosf(ang, &sn, &cs);
    float c = cs * sc, s = sn * sc;

    float* ptr = qkv + (size_t)row * QKV_LD + col;
    float2 x = *(float2*)ptr;
    float2 y;
    y.x = x.x * c - x.y * s;
    y.y = x.y * c + x.x * s;
    *(float2*)ptr = y;
}

// ---------------------------------------------------------------------------
// Retention: per (b,h), 64-row tile per block, flash-style over 32-row j-tiles.
// Thread (r = tid/4, part = tid%4): owns output cols [part*64, part*64+64),
// holds q[part*32..+32) in regs, partial dot reduced via shfl over 4 lanes.
// Fused decay mask + row scale + groupnorm epilogue. Writes `normed` (BT x V).
// ---------------------------------------------------------------------------
__global__ __launch_bounds__(256)
void retention_kernel(const float* __restrict__ qkv, float* __restrict__ normed)
{
    __shared__ float ks[32][128];
    __shared__ float vs[32][256];

    const int itile = 31 - (int)blockIdx.x;   // heavy tiles dispatched first
    const int bh = blockIdx.y;
    const int b = bh >> 3, h = bh & 7;
    const int tid = threadIdx.x;
    const int part = tid & 3;
    const int r = tid >> 2;                   // 0..63
    const int i = itile * 64 + r;             // global time index

    float ld, gamma;
    decay_params(h, ld, gamma);

    // q fragment: 32 floats
    float q[32];
    {
        const float* qp = qkv + (size_t)(b * T_SEQ + i) * QKV_LD + h * DK + part * 32;
        #pragma unroll
        for (int x = 0; x < 8; ++x)
            *(float4*)&q[x * 4] = *(const float4*)(qp + x * 4);
    }

    float o[64];
    #pragma unroll
    for (int x = 0; x < 64; ++x) o[x] = 0.0f;

    const int njt = itile * 2 + 2;
    for (int jt = 0; jt < njt; ++jt) {
        const int j0 = jt * 32;
        __syncthreads();
        {   // stage k tile: 32 x 128
            int jr = tid >> 5, c4 = tid & 31;
            #pragma unroll
            for (int ppp = 0; ppp < 4; ++ppp) {
                int jj = j0 + jr + ppp * 8;
                *(float4*)&ks[jr + ppp * 8][c4 * 4] =
                    *(const float4*)(qkv + (size_t)(b * T_SEQ + jj) * QKV_LD + E_DIM + h * DK + c4 * 4);
            }
            // stage v tile: 32 x 256
            int jr2 = tid >> 6, c42 = tid & 63;
            #pragma unroll
            for (int ppp = 0; ppp < 8; ++ppp) {
                int jj = j0 + jr2 + ppp * 4;
                *(float4*)&vs[jr2 + ppp * 4][c42 * 4] =
                    *(const float4*)(qkv + (size_t)(b * T_SEQ + jj) * QKV_LD + 2 * E_DIM + h * DV + c42 * 4);
            }
        }
        __syncthreads();

        for (int jj = 0; jj < 32; ++jj) {
            const int j = j0 + jj;
            float s = 0.0f;
            const float* kr = &ks[jj][part * 32];
            #pragma unroll
            for (int x = 0; x < 8; ++x) {
                float4 k4 = *(const float4*)(kr + x * 4);
                s = fmaf(q[x * 4 + 0], k4.x, s);
                s = fmaf(q[x * 4 + 1], k4.y, s);
                s = fmaf(q[x * 4 + 2], k4.z, s);
                s = fmaf(q[x * 4 + 3], k4.w, s);
            }
            s += __shfl_xor(s, 1);
            s += __shfl_xor(s, 2);
            s = (j <= i) ? s * expf(ld * (float)(i - j)) : 0.0f;

            const float* vr = &vs[jj][part * 64];
            #pragma unroll
            for (int x = 0; x < 16; ++x) {
                float4 v4 = *(const float4*)(vr + x * 4);
                o[x * 4 + 0] = fmaf(s, v4.x, o[x * 4 + 0]);
                o[x * 4 + 1] = fmaf(s, v4.y, o[x * 4 + 1]);
                o[x * 4 + 2] = fmaf(s, v4.z, o[x * 4 + 2]);
                o[x * 4 + 3] = fmaf(s, v4.w, o[x * 4 + 3]);
            }
        }
    }

    // final scale: dk^-0.5 / sqrt((1-gamma^(i+1))/(1-gamma))
    {
        float denom = (1.0f - expf(ld * (float)(i + 1))) / (1.0f - gamma);
        float fs = 0.08838834764831845f * rsqrtf(denom);
        #pragma unroll
        for (int x = 0; x < 64; ++x) o[x] *= fs;
    }

    // fused groupnorm over the 256 cols of (b, t=i, h): reduce across 4 lanes
    float s1 = 0.0f, s2 = 0.0f;
    #pragma unroll
    for (int x = 0; x < 64; ++x) { s1 += o[x]; s2 += o[x] * o[x]; }
    s1 += __shfl_xor(s1, 1); s1 += __shfl_xor(s1, 2);
    s2 += __shfl_xor(s2, 1); s2 += __shfl_xor(s2, 2);
    float mu = s1 * (1.0f / 256.0f);
    float var = s2 * (1.0f / 256.0f) - mu * mu;
    float rstd = rsqrtf(var + 1e-5f);

    float* np_ = normed + (size_t)(b * T_SEQ + i) * V_DIM + h * DV + part * 64;
    #pragma unroll
    for (int x = 0; x < 16; ++x) {
        float4 w4;
        w4.x = (o[x * 4 + 0] - mu) * rstd;
        w4.y = (o[x * 4 + 1] - mu) * rstd;
        w4.z = (o[x * 4 + 2] - mu) * rstd;
        w4.w = (o[x * 4 + 3] - mu) * rstd;
        *(float4*)(np_ + x * 4) = w4;
    }
}

// ---------------------------------------------------------------------------
// curr_kv[b,h,kk,vv] = sum_j gamma^(T-1-j)/scale_last * k[j,kk] * v[j,vv]
// block = (kk, b*H+h), 256 threads = vv. Weights*k staged in LDS (broadcast).
// ---------------------------------------------------------------------------
__global__ __launch_bounds__(256)
void currkv_kernel(const float* __restrict__ qkv, float* __restrict__ out)
{
    const int kk = blockIdx.x;
    const int bh = blockIdx.y;
    const int b = bh >> 3, h = bh & 7;
    const int t = threadIdx.x;   // vv

    float ld, gamma;
    decay_params(h, ld, gamma);
    float scale_last = sqrtf((1.0f - expf(ld * (float)T_SEQ)) / (1.0f - gamma));
    float inv_scale = 1.0f / scale_last;

    __shared__ float wk[256];
    float acc = 0.0f;
    for (int jt = 0; jt < T_SEQ; jt += 256) {
        __syncthreads();
        int j = jt + t;
        wk[t] = expf(ld * (float)(T_SEQ - 1 - j)) *
                qkv[(size_t)(b * T_SEQ + j) * QKV_LD + E_DIM + h * DK + kk];
        __syncthreads();
        const float* vbase = qkv + (size_t)(b * T_SEQ + jt) * QKV_LD + 2 * E_DIM + h * DV + t;
        #pragma unroll 8
        for (int jj = 0; jj < 256; ++jj)
            acc = fmaf(wk[jj], vbase[(size_t)jj * QKV_LD], acc);
    }
    out[((size_t)bh * DK + kk) * DV + t] = acc * inv_scale;
}

// ---------------------------------------------------------------------------
extern "C" void kernel_launch(void* const* d_in, const int* in_sizes, int n_in,
                              void* d_out, int out_size, void* d_ws, size_t ws_size,
                              hipStream_t stream)
{
    const float* hs    = (const float*)d_in[0];
    const float* w_qkv = (const float*)d_in[1];
    const float* b_qkv = (const float*)d_in[2];
    const float* w_g   = (const float*)d_in[3];
    const float* b_g   = (const float*)d_in[4];
    const float* w_p   = (const float*)d_in[5];
    const float* b_p   = (const float*)d_in[6];
    float* out = (float*)d_out;

    float* qkv    = (float*)d_ws;                    // BT x 4096 (q|k|v)
    float* normed = qkv + (size_t)BT * QKV_LD;       // BT x 2048

    dim3 blk(256);

    // 1. qkv = hs @ w_qkv + b_qkv
    gemm_kernel<0><<<dim3(32, 32), blk, 0, stream>>>(
        hs, E_DIM, w_qkv, 4096, b_qkv, qkv, QKV_LD, nullptr, 0, BT, 4096, E_DIM);

    // 2. xPos on q and k (in place)
    xpos_kernel<<<dim3(4, BT), blk, 0, stream>>>(qkv);

    // 3. retention + fused groupnorm -> normed
    retention_kernel<<<dim3(32, 16), blk, 0, stream>>>(qkv, normed);

    // 4. curr_kv -> second output region
    currkv_kernel<<<dim3(128, 16), blk, 0, stream>>>(qkv, out + (size_t)BT * E_DIM);

    // 5. gated = silu(hs @ w_g + b_g) * normed  -> stored into qkv cols [0,2048)
    gemm_kernel<1><<<dim3(16, 32), blk, 0, stream>>>(
        hs, E_DIM, w_g, V_DIM, b_g, qkv, QKV_LD, normed, V_DIM, BT, V_DIM, E_DIM);

    // 6. proj = gated @ w_p + b_p -> first output region
    gemm_kernel<0><<<dim3(8, 32), blk, 0, stream>>>(
        qkv, QKV_LD, w_p, E_DIM, b_p, out, E_DIM, nullptr, 0, BT, E_DIM, V_DIM);
}

// Round 2
// 1394.567 us; speedup vs baseline: 2.6471x; 2.6471x over previous
//
#include <hip/hip_runtime.h>
#include <math.h>

#define BT      4096
#define T_SEQ   2048
#define E_DIM   1024
#define V_DIM   2048
#define H_HEADS 8
#define DK      128
#define DV      256
#define QKV_LD  4096

typedef __attribute__((ext_vector_type(8)))  short bf16x8;
typedef __attribute__((ext_vector_type(16))) float f32x16;

__device__ __forceinline__ void decay_params(int h, float& ld, float& gamma) {
    const float s0 = -3.4657359027997265f;  // ln(1/32)
    const float e0 = -6.2383246250395092f;  // ln(1/512)
    float lin = s0 + (e0 - s0) * ((float)h * (1.0f / 7.0f));
    gamma = 1.0f - expf(lin);
    ld = logf(gamma);
}

__device__ __forceinline__ short f2bf(float f) {
    unsigned u = __float_as_uint(f);
    unsigned r = (u + 0x7fffu + ((u >> 16) & 1u)) >> 16;
    return (short)r;
}

// ---------------------------------------------------------------------------
// Generic tiled fp32 GEMM (unchanged from round 1)
// ---------------------------------------------------------------------------
template<int EPI>
__global__ __launch_bounds__(256)
void gemm_kernel(const float* __restrict__ A, int lda,
                 const float* __restrict__ Bm, int ldb,
                 const float* __restrict__ bias,
                 float* __restrict__ C, int ldc,
                 const float* __restrict__ extra, int lde,
                 int M, int N, int K)
{
    __shared__ float As[8][128];
    __shared__ float Bs[8][128];
    const int tid = threadIdx.x;
    const int n0 = blockIdx.x * 128;
    const int m0 = blockIdx.y * 128;

    const int arow = tid >> 1, aseg = tid & 1;
    const int brow = tid >> 5, bc4  = tid & 31;

    const float* Aptr = A + (size_t)(m0 + arow) * lda + aseg * 4;
    const float* Bptr = Bm + (size_t)brow * ldb + n0 + bc4 * 4;

    float4 a4 = *(const float4*)Aptr;
    float4 b4 = *(const float4*)Bptr;

    float acc[8][8];
    #pragma unroll
    for (int i = 0; i < 8; ++i)
        #pragma unroll
        for (int j = 0; j < 8; ++j) acc[i][j] = 0.0f;

    const int tx = tid & 15, ty = tid >> 4;

    const int nk = K >> 3;
    for (int kt = 0; kt < nk; ++kt) {
        As[aseg * 4 + 0][arow] = a4.x;
        As[aseg * 4 + 1][arow] = a4.y;
        As[aseg * 4 + 2][arow] = a4.z;
        As[aseg * 4 + 3][arow] = a4.w;
        *(float4*)&Bs[brow][bc4 * 4] = b4;
        __syncthreads();
        if (kt + 1 < nk) {
            a4 = *(const float4*)(Aptr + (kt + 1) * 8);
            b4 = *(const float4*)(Bptr + (size_t)(kt + 1) * 8 * ldb);
        }
        #pragma unroll
        for (int kk = 0; kk < 8; ++kk) {
            float ar[8], br[8];
            *(float4*)&ar[0] = *(const float4*)&As[kk][ty * 4];
            *(float4*)&ar[4] = *(const float4*)&As[kk][64 + ty * 4];
            *(float4*)&br[0] = *(const float4*)&Bs[kk][tx * 4];
            *(float4*)&br[4] = *(const float4*)&Bs[kk][64 + tx * 4];
            #pragma unroll
            for (int i = 0; i < 8; ++i)
                #pragma unroll
                for (int j = 0; j < 8; ++j)
                    acc[i][j] = fmaf(ar[i], br[j], acc[i][j]);
        }
        __syncthreads();
    }

    #pragma unroll
    for (int ii = 0; ii < 8; ++ii) {
        int m = m0 + ((ii < 4) ? (ty * 4 + ii) : (64 + ty * 4 + ii - 4));
        #pragma unroll
        for (int jh = 0; jh < 2; ++jh) {
            int n = n0 + jh * 64 + tx * 4;
            float4 bb = *(const float4*)&bias[n];
            const float* av = &acc[ii][jh * 4];
            float4 res;
            res.x = av[0] + bb.x;
            res.y = av[1] + bb.y;
            res.z = av[2] + bb.z;
            res.w = av[3] + bb.w;
            if (EPI == 1) {
                float4 ex = *(const float4*)&extra[(size_t)m * lde + n];
                res.x = res.x / (1.0f + expf(-res.x)) * ex.x;
                res.y = res.y / (1.0f + expf(-res.y)) * ex.y;
                res.z = res.z / (1.0f + expf(-res.z)) * ex.z;
                res.w = res.w / (1.0f + expf(-res.w)) * ex.w;
            }
            *(float4*)&C[(size_t)m * ldc + n] = res;
        }
    }
}

// ---------------------------------------------------------------------------
// xPos rotary (unchanged)
// ---------------------------------------------------------------------------
__global__ __launch_bounds__(256)
void xpos_kernel(float* __restrict__ qkv)
{
    int p = blockIdx.x * 256 + threadIdx.x;
    int row = blockIdx.y;
    int t = row & (T_SEQ - 1);
    bool isK = p >= 512;
    int ip = isK ? (p - 512) : p;
    int col = (isK ? E_DIM : 0) + 2 * ip;

    float sv = (2.0f * (float)ip + 409.6f) * (1.0f / 1433.6f);
    float sc = powf(sv, (float)t * (1.0f / 512.0f));
    if (isK) sc = 1.0f / sc;
    float invf = powf(10000.0f, -(float)ip * (1.0f / 512.0f));
    float ang = (float)t * invf;
    float sn, cs;
    sincosf(ang, &sn, &cs);
    float c = cs * sc, s = sn * sc;

    float* ptr = qkv + (size_t)row * QKV_LD + col;
    float2 x = *(float2*)ptr;
    float2 y;
    y.x = x.x * c - x.y * s;
    y.y = x.y * c + x.x * s;
    *(float2*)ptr = y;
}

// ---------------------------------------------------------------------------
// MFMA retention. Block = 128 threads = 2 waves; block g handles i-tiles
// 2g (wave0) and 2g+1 (wave1), 32 rows each. Flash loop over 32-row j-tiles,
// K and V^T staged in LDS as bf16 (conflict-free b128 layout), Q fragments
// in registers. Decay folded into staging scales + per-tile scalar.
// S^T = K.Q^T via mfma_32x32x16_bf16 (C col = i = lane&31 matches A-operand
// m = lane&31 for P.V; k-index fixed via shfl_xor(32)). Fused groupnorm.
// ---------------------------------------------------------------------------
__global__ __launch_bounds__(128)
void retention_mfma(const float* __restrict__ qkv, float* __restrict__ normed)
{
    __shared__ short Ks[32][136];   // bf16 K tile  [j][d], stride 136 (272B, 16B-aligned)
    __shared__ short Vt[256][40];   // bf16 V^T tile [v][j], stride 40 (80B, 16B-aligned)

    const int g  = 31 - (int)blockIdx.x;        // heavy blocks first
    const int bh = blockIdx.y;
    const int b  = bh >> 3, h = bh & 7;
    const int tid = threadIdx.x;
    const int w  = tid >> 6;                    // wave id 0/1
    const int l  = tid & 63;
    const int lc = l & 31;                      // lane-in-half: i (or v) column
    const int q  = l >> 5;                      // half-wave select
    const int it = 2 * g + w;                   // this wave's i-tile
    const int i0 = it * 32;

    float ld, gamma;
    decay_params(h, ld, gamma);

    // ---- Q fragments, resident in registers for the whole kernel ----
    // B-operand layout: n = lane&31 (Q row i0+lc), k = 8q + e per 16-chunk.
    bf16x8 qf[8];
    {
        const float qs = expf(ld * (float)lc);          // gamma^(i - i0)
        const float* qp = qkv + (size_t)(b * T_SEQ + i0 + lc) * QKV_LD + h * DK + q * 8;
        #pragma unroll
        for (int c = 0; c < 8; ++c) {
            float4 x0 = *(const float4*)(qp + c * 16);
            float4 x1 = *(const float4*)(qp + c * 16 + 4);
            bf16x8 f;
            f[0] = f2bf(x0.x * qs); f[1] = f2bf(x0.y * qs);
            f[2] = f2bf(x0.z * qs); f[3] = f2bf(x0.w * qs);
            f[4] = f2bf(x1.x * qs); f[5] = f2bf(x1.y * qs);
            f[6] = f2bf(x1.z * qs); f[7] = f2bf(x1.w * qs);
            qf[c] = f;
        }
    }

    f32x16 acc[8];
    #pragma unroll
    for (int vg = 0; vg < 8; ++vg)
        #pragma unroll
        for (int e = 0; e < 16; ++e) acc[vg][e] = 0.0f;

    const int njt = 2 * g + 2;
    for (int jt = 0; jt < njt; ++jt) {
        const int j0 = jt * 32;
        __syncthreads();

        // ---- stage K tile: rows j0..j0+31, scaled by gamma^(j0-j) ----
        {
            const int jr = tid >> 2, seg = (tid & 3) * 32;
            const float ks = expf(-ld * (float)jr);     // gamma^(-(j-j0)) >= 1
            const float* kp = qkv + (size_t)(b * T_SEQ + j0 + jr) * QKV_LD + E_DIM + h * DK + seg;
            #pragma unroll
            for (int c = 0; c < 4; ++c) {
                float4 x0 = *(const float4*)(kp + c * 8);
                float4 x1 = *(const float4*)(kp + c * 8 + 4);
                bf16x8 f;
                f[0] = f2bf(x0.x * ks); f[1] = f2bf(x0.y * ks);
                f[2] = f2bf(x0.z * ks); f[3] = f2bf(x0.w * ks);
                f[4] = f2bf(x1.x * ks); f[5] = f2bf(x1.y * ks);
                f[6] = f2bf(x1.z * ks); f[7] = f2bf(x1.w * ks);
                *(bf16x8*)&Ks[jr][seg + c * 8] = f;
            }
        }
        // ---- stage V^T tile: Vt[v][j] ----
        {
            #pragma unroll
            for (int half = 0; half < 2; ++half) {
                const int v = tid + half * 128;
                const float* vp = qkv + (size_t)(b * T_SEQ + j0) * QKV_LD + 2 * E_DIM + h * DV + v;
                short tmp[32];
                #pragma unroll
                for (int j = 0; j < 32; ++j)
                    tmp[j] = f2bf(vp[(size_t)j * QKV_LD]);
                #pragma unroll
                for (int s = 0; s < 4; ++s) {
                    bf16x8 f;
                    #pragma unroll
                    for (int e = 0; e < 8; ++e) f[e] = tmp[s * 8 + e];
                    *(bf16x8*)&Vt[v][s * 8] = f;
                }
            }
        }
        __syncthreads();

        if (jt > it) continue;   // wave-uniform; both barriers already hit

        // ---- S^T = K . Q^T : A = K (m=j=lane&31), B = Q^T ----
        f32x16 s;
        #pragma unroll
        for (int e = 0; e < 16; ++e) s[e] = 0.0f;
        #pragma unroll
        for (int c = 0; c < 8; ++c) {
            bf16x8 ka = *(const bf16x8*)&Ks[lc][c * 16 + q * 8];
            s = __builtin_amdgcn_mfma_f32_32x32x16_bf16(ka, qf[c], s, 0, 0, 0);
        }

        // ---- mask + per-tile decay scalar ----
        const float csc = expf(ld * (float)(i0 - j0));  // gamma^(i0-j0) <= 1
        float sv[16];
        #pragma unroll
        for (int r = 0; r < 16; ++r) {
            float val = s[r] * csc;
            if (jt == it) {
                int jr_ = (r & 3) + 8 * (r >> 2) + 4 * q;   // row (=j) of this reg
                val = (jr_ <= lc) ? val : 0.0f;             // keep j <= i
            }
            sv[r] = val;
        }

        // ---- transform S^T (C-layout) -> P A-operand fragments ----
        // chunk0 (j in [0,16)):  q=0: {sv0..3, t(sv0..3)} ; q=1: {t(sv4..7), sv4..7}
        // chunk1 (j in [16,32)): q=0: {sv8..11,t(sv8..11)}; q=1: {t(sv12..15), sv12..15}
        bf16x8 pa0, pa1;
        #pragma unroll
        for (int e = 0; e < 4; ++e) {
            float t1 = __shfl_xor(sv[e + 4], 32);
            float t0 = __shfl_xor(sv[e], 32);
            pa0[e]     = f2bf(q ? t1 : sv[e]);
            pa0[e + 4] = f2bf(q ? sv[e + 4] : t0);
            float t3 = __shfl_xor(sv[e + 12], 32);
            float t2 = __shfl_xor(sv[e + 8], 32);
            pa1[e]     = f2bf(q ? t3 : sv[e + 8]);
            pa1[e + 4] = f2bf(q ? sv[e + 12] : t2);
        }

        // ---- O += P . V : B from Vt (n=v=lane&31, k=j=16c+8q+e) ----
        #pragma unroll
        for (int vg = 0; vg < 8; ++vg) {
            bf16x8 vb0 = *(const bf16x8*)&Vt[vg * 32 + lc][q * 8];
            bf16x8 vb1 = *(const bf16x8*)&Vt[vg * 32 + lc][16 + q * 8];
            acc[vg] = __builtin_amdgcn_mfma_f32_32x32x16_bf16(pa0, vb0, acc[vg], 0, 0, 0);
            acc[vg] = __builtin_amdgcn_mfma_f32_32x32x16_bf16(pa1, vb1, acc[vg], 0, 0, 0);
        }
    }

    // ---- epilogue: row scale + fused groupnorm + store ----
    // C-layout: col v = vg*32 + lc, row i_local = (r&3) + 8*(r>>2) + 4q
    #pragma unroll
    for (int r = 0; r < 16; ++r) {
        const int il = (r & 3) + 8 * (r >> 2) + 4 * q;
        const int i  = i0 + il;
        float denom = (1.0f - expf(ld * (float)(i + 1))) / (1.0f - gamma);
        float fs = 0.08838834764831845f * rsqrtf(denom);   // dk^-0.5 / sqrt(rowsum)
        float vals[8];
        float a1 = 0.0f, a2 = 0.0f;
        #pragma unroll
        for (int vg = 0; vg < 8; ++vg) {
            float x = acc[vg][r] * fs;
            vals[vg] = x;
            a1 += x; a2 += x * x;
        }
        a1 += __shfl_xor(a1, 1);  a2 += __shfl_xor(a2, 1);
        a1 += __shfl_xor(a1, 2);  a2 += __shfl_xor(a2, 2);
        a1 += __shfl_xor(a1, 4);  a2 += __shfl_xor(a2, 4);
        a1 += __shfl_xor(a1, 8);  a2 += __shfl_xor(a2, 8);
        a1 += __shfl_xor(a1, 16); a2 += __shfl_xor(a2, 16);
        float mu = a1 * (1.0f / 256.0f);
        float var = a2 * (1.0f / 256.0f) - mu * mu;
        float rs = rsqrtf(var + 1e-5f);
        float* op = normed + (size_t)(b * T_SEQ + i) * V_DIM + h * DV + lc;
        #pragma unroll
        for (int vg = 0; vg < 8; ++vg)
            op[vg * 32] = (vals[vg] - mu) * rs;
    }
}

// ---------------------------------------------------------------------------
// curr_kv (unchanged)
// ---------------------------------------------------------------------------
__global__ __launch_bounds__(256)
void currkv_kernel(const float* __restrict__ qkv, float* __restrict__ out)
{
    const int kk = blockIdx.x;
    const int bh = blockIdx.y;
    const int b = bh >> 3, h = bh & 7;
    const int t = threadIdx.x;

    float ld, gamma;
    decay_params(h, ld, gamma);
    float scale_last = sqrtf((1.0f - expf(ld * (float)T_SEQ)) / (1.0f - gamma));
    float inv_scale = 1.0f / scale_last;

    __shared__ float wk[256];
    float acc = 0.0f;
    for (int jt = 0; jt < T_SEQ; jt += 256) {
        __syncthreads();
        int j = jt + t;
        wk[t] = expf(ld * (float)(T_SEQ - 1 - j)) *
                qkv[(size_t)(b * T_SEQ + j) * QKV_LD + E_DIM + h * DK + kk];
        __syncthreads();
        const float* vbase = qkv + (size_t)(b * T_SEQ + jt) * QKV_LD + 2 * E_DIM + h * DV + t;
        #pragma unroll 8
        for (int jj = 0; jj < 256; ++jj)
            acc = fmaf(wk[jj], vbase[(size_t)jj * QKV_LD], acc);
    }
    out[((size_t)bh * DK + kk) * DV + t] = acc * inv_scale;
}

// ---------------------------------------------------------------------------
extern "C" void kernel_launch(void* const* d_in, const int* in_sizes, int n_in,
                              void* d_out, int out_size, void* d_ws, size_t ws_size,
                              hipStream_t stream)
{
    const float* hs    = (const float*)d_in[0];
    const float* w_qkv = (const float*)d_in[1];
    const float* b_qkv = (const float*)d_in[2];
    const float* w_g   = (const float*)d_in[3];
    const float* b_g   = (const float*)d_in[4];
    const float* w_p   = (const float*)d_in[5];
    const float* b_p   = (const float*)d_in[6];
    float* out = (float*)d_out;

    float* qkv    = (float*)d_ws;                    // BT x 4096 (q|k|v)
    float* normed = qkv + (size_t)BT * QKV_LD;       // BT x 2048

    // 1. qkv = hs @ w_qkv + b_qkv
    gemm_kernel<0><<<dim3(32, 32), 256, 0, stream>>>(
        hs, E_DIM, w_qkv, 4096, b_qkv, qkv, QKV_LD, nullptr, 0, BT, 4096, E_DIM);

    // 2. xPos on q and k (in place)
    xpos_kernel<<<dim3(4, BT), 256, 0, stream>>>(qkv);

    // 3. retention + fused groupnorm -> normed  (bf16 MFMA)
    retention_mfma<<<dim3(32, 16), 128, 0, stream>>>(qkv, normed);

    // 4. curr_kv -> second output region
    currkv_kernel<<<dim3(128, 16), 256, 0, stream>>>(qkv, out + (size_t)BT * E_DIM);

    // 5. gated = silu(hs @ w_g + b_g) * normed -> qkv cols [0,2048)
    gemm_kernel<1><<<dim3(16, 32), 256, 0, stream>>>(
        hs, E_DIM, w_g, V_DIM, b_g, qkv, QKV_LD, normed, V_DIM, BT, V_DIM, E_DIM);

    // 6. proj = gated @ w_p + b_p -> first output region
    gemm_kernel<0><<<dim3(8, 32), 256, 0, stream>>>(
        qkv, QKV_LD, w_p, E_DIM, b_p, out, E_DIM, nullptr, 0, BT, E_DIM, V_DIM);
}

// Round 3
// 607.372 us; speedup vs baseline: 6.0779x; 2.2961x over previous
//
#include <hip/hip_runtime.h>
#include <math.h>

#define BT      4096
#define T_SEQ   2048
#define E_DIM   1024
#define V_DIM   2048
#define DK      128
#define DV      256
#define QKV_LD  4096

typedef unsigned short ushort_t;
typedef __attribute__((ext_vector_type(8)))  short bf16x8;
typedef __attribute__((ext_vector_type(4)))  unsigned short u16x4;
typedef __attribute__((ext_vector_type(16))) float f32x16;

__device__ __forceinline__ void decay_params(int h, float& ld, float& gamma) {
    const float s0 = -3.4657359027997265f;  // ln(1/32)
    const float e0 = -6.2383246250395092f;  // ln(1/512)
    float lin = s0 + (e0 - s0) * ((float)h * (1.0f / 7.0f));
    gamma = 1.0f - expf(lin);
    ld = logf(gamma);
}

__device__ __forceinline__ short f2bf(float f) {
    unsigned u = __float_as_uint(f);
    unsigned r = (u + 0x7fffu + ((u >> 16) & 1u)) >> 16;
    return (short)r;
}

// async 16B global -> LDS (global_load_lds_dwordx4); LDS dest is
// wave-uniform base + lane*16.
__device__ __forceinline__ void async_copy16(void* lds, const void* g) {
    __builtin_amdgcn_global_load_lds(
        (const __attribute__((address_space(1))) unsigned int*)g,
        (__attribute__((address_space(3))) unsigned int*)lds, 16, 0, 0);
}

// ---------------------------------------------------------------------------
// fp32 -> bf16 elementwise (for hidden_states). 8 elems/thread.
// ---------------------------------------------------------------------------
__global__ __launch_bounds__(256)
void f32_to_bf16_kernel(const float* __restrict__ in, ushort_t* __restrict__ out)
{
    int i = (blockIdx.x * 256 + threadIdx.x) * 8;
    float4 a = *(const float4*)&in[i];
    float4 b = *(const float4*)&in[i + 4];
    bf16x8 o;
    o[0] = f2bf(a.x); o[1] = f2bf(a.y); o[2] = f2bf(a.z); o[3] = f2bf(a.w);
    o[4] = f2bf(b.x); o[5] = f2bf(b.y); o[6] = f2bf(b.z); o[7] = f2bf(b.w);
    *(bf16x8*)&out[i] = o;
}

// ---------------------------------------------------------------------------
// W[K][N] fp32 -> Wt[N][K] bf16 (32x32 LDS tile transpose)
// ---------------------------------------------------------------------------
__global__ __launch_bounds__(256)
void transpose_w_kernel(const float* __restrict__ W, ushort_t* __restrict__ Wt,
                        int K, int N)
{
    __shared__ float tile[32][33];
    const int k0 = blockIdx.y * 32, n0 = blockIdx.x * 32;
    const int t = threadIdx.x;
    const int r = t >> 3, c = (t & 7) * 4;
    float4 v = *(const float4*)&W[(size_t)(k0 + r) * N + n0 + c];
    tile[r][c] = v.x; tile[r][c + 1] = v.y; tile[r][c + 2] = v.z; tile[r][c + 3] = v.w;
    __syncthreads();
    const int n = r, k = c;   // same decomposition, transposed roles
    u16x4 o;
    o[0] = (ushort_t)f2bf(tile[k][n]);
    o[1] = (ushort_t)f2bf(tile[k + 1][n]);
    o[2] = (ushort_t)f2bf(tile[k + 2][n]);
    o[3] = (ushort_t)f2bf(tile[k + 3][n]);
    *(u16x4*)&Wt[(size_t)(n0 + n) * K + k0 + k] = o;
}

// ---------------------------------------------------------------------------
// bf16 MFMA GEMM: C(M,N) = A(M,K) @ B(K,N) + bias
//   A  : bf16 [M][lda], k-contiguous
//   Bt : bf16 [N][ldb], k-contiguous (pre-transposed weights)
// 128x128 tile, BK=32, 256 threads = 4 waves (2x2 of 64x64), each wave 2x2
// mfma_32x32x16. Staging via global_load_lds width=16; 16B-chunk XOR swizzle
// (kc ^ (row>>1)&3) makes fragment ds_read_b128 conflict-free.
// EPI 0: fp32 out = acc + bias
// EPI 1: bf16 out = silu(acc + bias) * extra[row][col]
// ---------------------------------------------------------------------------
template<int EPI>
__global__ __launch_bounds__(256)
void gemm_bf16(const ushort_t* __restrict__ A, int lda,
               const ushort_t* __restrict__ Bt, int ldb,
               const float* __restrict__ bias,
               void* __restrict__ Cv, int ldc,
               const float* __restrict__ extra, int lde,
               int nkt)
{
    __shared__ ushort_t As[128 * 32];
    __shared__ ushort_t Bs[128 * 32];

    const int tid = threadIdx.x;
    const int w  = tid >> 6, l = tid & 63;
    const int lc = l & 31, q = l >> 5;
    const int wr = w >> 1, wc = w & 1;
    const int m0 = blockIdx.y * 128, n0 = blockIdx.x * 128;

    // staging: chunk ci = issue*256 + tid; row = ci>>2; stored kcs = ci&3
    // holds global kc = kcs ^ ((row>>1)&3)
    const int r0 = tid >> 2,        kc0 = (tid & 3) ^ ((r0 >> 1) & 3);
    const int r1 = (256 + tid) >> 2, kc1 = (tid & 3) ^ ((r1 >> 1) & 3);
    const ushort_t* gA0 = A  + (size_t)(m0 + r0) * lda + kc0 * 8;
    const ushort_t* gA1 = A  + (size_t)(m0 + r1) * lda + kc1 * 8;
    const ushort_t* gB0 = Bt + (size_t)(n0 + r0) * ldb + kc0 * 8;
    const ushort_t* gB1 = Bt + (size_t)(n0 + r1) * ldb + kc1 * 8;
    ushort_t* lA0 = &As[(w * 64) * 8];
    ushort_t* lA1 = &As[(256 + w * 64) * 8];
    ushort_t* lB0 = &Bs[(w * 64) * 8];
    ushort_t* lB1 = &Bs[(256 + w * 64) * 8];

    // fragment pointers (constant; single-buffered LDS)
    const int sl = (lc >> 1) & 3;
    const bf16x8* apt[2][2];
    const bf16x8* bpt[2][2];
    #pragma unroll
    for (int mi = 0; mi < 2; ++mi)
        #pragma unroll
        for (int ks = 0; ks < 2; ++ks) {
            const int kc = ks * 2 + q;
            const int mrow = wr * 64 + mi * 32 + lc;
            const int nrow = wc * 64 + mi * 32 + lc;
            apt[mi][ks] = (const bf16x8*)&As[(mrow * 4 + (kc ^ sl)) * 8];
            bpt[mi][ks] = (const bf16x8*)&Bs[(nrow * 4 + (kc ^ sl)) * 8];
        }

    f32x16 acc[2][2];
    #pragma unroll
    for (int mi = 0; mi < 2; ++mi)
        #pragma unroll
        for (int ni = 0; ni < 2; ++ni)
            #pragma unroll
            for (int e = 0; e < 16; ++e) acc[mi][ni][e] = 0.0f;

    for (int kt = 0; kt < nkt; ++kt) {
        async_copy16(lA0, gA0); async_copy16(lA1, gA1);
        async_copy16(lB0, gB0); async_copy16(lB1, gB1);
        gA0 += 32; gA1 += 32; gB0 += 32; gB1 += 32;
        __syncthreads();

        bf16x8 a[2][2], b[2][2];
        #pragma unroll
        for (int mi = 0; mi < 2; ++mi)
            #pragma unroll
            for (int ks = 0; ks < 2; ++ks) {
                a[mi][ks] = *apt[mi][ks];
                b[mi][ks] = *bpt[mi][ks];
            }
        #pragma unroll
        for (int ks = 0; ks < 2; ++ks)
            #pragma unroll
            for (int mi = 0; mi < 2; ++mi)
                #pragma unroll
                for (int ni = 0; ni < 2; ++ni)
                    acc[mi][ni] = __builtin_amdgcn_mfma_f32_32x32x16_bf16(
                        a[mi][ks], b[ni][ks], acc[mi][ni], 0, 0, 0);
        __syncthreads();
    }

    // epilogue: C/D layout col = lane&31, row = (r&3)+8*(r>>2)+4*q
    #pragma unroll
    for (int ni = 0; ni < 2; ++ni) {
        const int col = n0 + wc * 64 + ni * 32 + lc;
        const float bb = bias[col];
        #pragma unroll
        for (int mi = 0; mi < 2; ++mi) {
            #pragma unroll
            for (int r = 0; r < 16; ++r) {
                const int row = m0 + wr * 64 + mi * 32 + (r & 3) + 8 * (r >> 2) + 4 * q;
                float val = acc[mi][ni][r] + bb;
                if (EPI == 0) {
                    ((float*)Cv)[(size_t)row * ldc + col] = val;
                } else {
                    const float e = extra[(size_t)row * lde + col];
                    val = val / (1.0f + expf(-val)) * e;
                    ((ushort_t*)Cv)[(size_t)row * ldc + col] = (ushort_t)f2bf(val);
                }
            }
        }
    }
}

// ---------------------------------------------------------------------------
// xPos rotary (unchanged)
// ---------------------------------------------------------------------------
__global__ __launch_bounds__(256)
void xpos_kernel(float* __restrict__ qkv)
{
    int p = blockIdx.x * 256 + threadIdx.x;
    int row = blockIdx.y;
    int t = row & (T_SEQ - 1);
    bool isK = p >= 512;
    int ip = isK ? (p - 512) : p;
    int col = (isK ? E_DIM : 0) + 2 * ip;

    float sv = (2.0f * (float)ip + 409.6f) * (1.0f / 1433.6f);
    float sc = powf(sv, (float)t * (1.0f / 512.0f));
    if (isK) sc = 1.0f / sc;
    float invf = powf(10000.0f, -(float)ip * (1.0f / 512.0f));
    float ang = (float)t * invf;
    float sn, cs;
    sincosf(ang, &sn, &cs);
    float c = cs * sc, s = sn * sc;

    float* ptr = qkv + (size_t)row * QKV_LD + col;
    float2 x = *(float2*)ptr;
    float2 y;
    y.x = x.x * c - x.y * s;
    y.y = x.y * c + x.x * s;
    *(float2*)ptr = y;
}

// ---------------------------------------------------------------------------
// MFMA retention (unchanged from round 2, verified)
// ---------------------------------------------------------------------------
__global__ __launch_bounds__(128)
void retention_mfma(const float* __restrict__ qkv, float* __restrict__ normed)
{
    __shared__ short Ks[32][136];
    __shared__ short Vt[256][40];

    const int g  = 31 - (int)blockIdx.x;
    const int bh = blockIdx.y;
    const int b  = bh >> 3, h = bh & 7;
    const int tid = threadIdx.x;
    const int w  = tid >> 6;
    const int l  = tid & 63;
    const int lc = l & 31;
    const int q  = l >> 5;
    const int it = 2 * g + w;
    const int i0 = it * 32;

    float ld, gamma;
    decay_params(h, ld, gamma);

    bf16x8 qf[8];
    {
        const float qs = expf(ld * (float)lc);
        const float* qp = qkv + (size_t)(b * T_SEQ + i0 + lc) * QKV_LD + h * DK + q * 8;
        #pragma unroll
        for (int c = 0; c < 8; ++c) {
            float4 x0 = *(const float4*)(qp + c * 16);
            float4 x1 = *(const float4*)(qp + c * 16 + 4);
            bf16x8 f;
            f[0] = f2bf(x0.x * qs); f[1] = f2bf(x0.y * qs);
            f[2] = f2bf(x0.z * qs); f[3] = f2bf(x0.w * qs);
            f[4] = f2bf(x1.x * qs); f[5] = f2bf(x1.y * qs);
            f[6] = f2bf(x1.z * qs); f[7] = f2bf(x1.w * qs);
            qf[c] = f;
        }
    }

    f32x16 acc[8];
    #pragma unroll
    for (int vg = 0; vg < 8; ++vg)
        #pragma unroll
        for (int e = 0; e < 16; ++e) acc[vg][e] = 0.0f;

    const int njt = 2 * g + 2;
    for (int jt = 0; jt < njt; ++jt) {
        const int j0 = jt * 32;
        __syncthreads();
        {
            const int jr = tid >> 2, seg = (tid & 3) * 32;
            const float ks = expf(-ld * (float)jr);
            const float* kp = qkv + (size_t)(b * T_SEQ + j0 + jr) * QKV_LD + E_DIM + h * DK + seg;
            #pragma unroll
            for (int c = 0; c < 4; ++c) {
                float4 x0 = *(const float4*)(kp + c * 8);
                float4 x1 = *(const float4*)(kp + c * 8 + 4);
                bf16x8 f;
                f[0] = f2bf(x0.x * ks); f[1] = f2bf(x0.y * ks);
                f[2] = f2bf(x0.z * ks); f[3] = f2bf(x0.w * ks);
                f[4] = f2bf(x1.x * ks); f[5] = f2bf(x1.y * ks);
                f[6] = f2bf(x1.z * ks); f[7] = f2bf(x1.w * ks);
                *(bf16x8*)&Ks[jr][seg + c * 8] = f;
            }
        }
        {
            #pragma unroll
            for (int half = 0; half < 2; ++half) {
                const int v = tid + half * 128;
                const float* vp = qkv + (size_t)(b * T_SEQ + j0) * QKV_LD + 2 * E_DIM + h * DV + v;
                short tmp[32];
                #pragma unroll
                for (int j = 0; j < 32; ++j)
                    tmp[j] = f2bf(vp[(size_t)j * QKV_LD]);
                #pragma unroll
                for (int s = 0; s < 4; ++s) {
                    bf16x8 f;
                    #pragma unroll
                    for (int e = 0; e < 8; ++e) f[e] = tmp[s * 8 + e];
                    *(bf16x8*)&Vt[v][s * 8] = f;
                }
            }
        }
        __syncthreads();

        if (jt > it) continue;

        f32x16 s;
        #pragma unroll
        for (int e = 0; e < 16; ++e) s[e] = 0.0f;
        #pragma unroll
        for (int c = 0; c < 8; ++c) {
            bf16x8 ka = *(const bf16x8*)&Ks[lc][c * 16 + q * 8];
            s = __builtin_amdgcn_mfma_f32_32x32x16_bf16(ka, qf[c], s, 0, 0, 0);
        }

        const float csc = expf(ld * (float)(i0 - j0));
        float sv[16];
        #pragma unroll
        for (int r = 0; r < 16; ++r) {
            float val = s[r] * csc;
            if (jt == it) {
                int jr_ = (r & 3) + 8 * (r >> 2) + 4 * q;
                val = (jr_ <= lc) ? val : 0.0f;
            }
            sv[r] = val;
        }

        bf16x8 pa0, pa1;
        #pragma unroll
        for (int e = 0; e < 4; ++e) {
            float t1 = __shfl_xor(sv[e + 4], 32);
            float t0 = __shfl_xor(sv[e], 32);
            pa0[e]     = f2bf(q ? t1 : sv[e]);
            pa0[e + 4] = f2bf(q ? sv[e + 4] : t0);
            float t3 = __shfl_xor(sv[e + 12], 32);
            float t2 = __shfl_xor(sv[e + 8], 32);
            pa1[e]     = f2bf(q ? t3 : sv[e + 8]);
            pa1[e + 4] = f2bf(q ? sv[e + 12] : t2);
        }

        #pragma unroll
        for (int vg = 0; vg < 8; ++vg) {
            bf16x8 vb0 = *(const bf16x8*)&Vt[vg * 32 + lc][q * 8];
            bf16x8 vb1 = *(const bf16x8*)&Vt[vg * 32 + lc][16 + q * 8];
            acc[vg] = __builtin_amdgcn_mfma_f32_32x32x16_bf16(pa0, vb0, acc[vg], 0, 0, 0);
            acc[vg] = __builtin_amdgcn_mfma_f32_32x32x16_bf16(pa1, vb1, acc[vg], 0, 0, 0);
        }
    }

    #pragma unroll
    for (int r = 0; r < 16; ++r) {
        const int il = (r & 3) + 8 * (r >> 2) + 4 * q;
        const int i  = i0 + il;
        float denom = (1.0f - expf(ld * (float)(i + 1))) / (1.0f - gamma);
        float fs = 0.08838834764831845f * rsqrtf(denom);
        float vals[8];
        float a1 = 0.0f, a2 = 0.0f;
        #pragma unroll
        for (int vg = 0; vg < 8; ++vg) {
            float x = acc[vg][r] * fs;
            vals[vg] = x;
            a1 += x; a2 += x * x;
        }
        a1 += __shfl_xor(a1, 1);  a2 += __shfl_xor(a2, 1);
        a1 += __shfl_xor(a1, 2);  a2 += __shfl_xor(a2, 2);
        a1 += __shfl_xor(a1, 4);  a2 += __shfl_xor(a2, 4);
        a1 += __shfl_xor(a1, 8);  a2 += __shfl_xor(a2, 8);
        a1 += __shfl_xor(a1, 16); a2 += __shfl_xor(a2, 16);
        float mu = a1 * (1.0f / 256.0f);
        float var = a2 * (1.0f / 256.0f) - mu * mu;
        float rs = rsqrtf(var + 1e-5f);
        float* op = normed + (size_t)(b * T_SEQ + i) * V_DIM + h * DV + lc;
        #pragma unroll
        for (int vg = 0; vg < 8; ++vg)
            op[vg * 32] = (vals[vg] - mu) * rs;
    }
}

// ---------------------------------------------------------------------------
// curr_kv restructured: block = (kk-group of 8, bh); 256 threads = vv.
// Weighted k staged in LDS, read back as broadcast float4.
// ---------------------------------------------------------------------------
__global__ __launch_bounds__(256)
void currkv_kernel(const float* __restrict__ qkv, float* __restrict__ out)
{
    const int kk0 = blockIdx.x * 8;
    const int bh = blockIdx.y;
    const int b = bh >> 3, h = bh & 7;
    const int t = threadIdx.x;

    float ld, gamma;
    decay_params(h, ld, gamma);
    float inv_scale = rsqrtf((1.0f - expf(ld * (float)T_SEQ)) / (1.0f - gamma));

    __shared__ float wk[8][260];
    float acc[8];
    #pragma unroll
    for (int c = 0; c < 8; ++c) acc[c] = 0.0f;

    for (int jt = 0; jt < T_SEQ; jt += 256) {
        __syncthreads();
        {
            float wgt = expf(ld * (float)(T_SEQ - 1 - jt - t));
            const float* kp = qkv + (size_t)(b * T_SEQ + jt + t) * QKV_LD + E_DIM + h * DK + kk0;
            float4 k0 = *(const float4*)kp;
            float4 k1 = *(const float4*)(kp + 4);
            wk[0][t] = k0.x * wgt; wk[1][t] = k0.y * wgt;
            wk[2][t] = k0.z * wgt; wk[3][t] = k0.w * wgt;
            wk[4][t] = k1.x * wgt; wk[5][t] = k1.y * wgt;
            wk[6][t] = k1.z * wgt; wk[7][t] = k1.w * wgt;
        }
        __syncthreads();
        const float* vp = qkv + (size_t)(b * T_SEQ + jt) * QKV_LD + 2 * E_DIM + h * DV + t;
        #pragma unroll 2
        for (int g = 0; g < 64; ++g) {
            float4 w4[8];
            #pragma unroll
            for (int c = 0; c < 8; ++c) w4[c] = *(const float4*)&wk[c][g * 4];
            float v0 = vp[(size_t)(g * 4 + 0) * QKV_LD];
            float v1 = vp[(size_t)(g * 4 + 1) * QKV_LD];
            float v2 = vp[(size_t)(g * 4 + 2) * QKV_LD];
            float v3 = vp[(size_t)(g * 4 + 3) * QKV_LD];
            #pragma unroll
            for (int c = 0; c < 8; ++c) {
                acc[c] = fmaf(w4[c].x, v0, acc[c]);
                acc[c] = fmaf(w4[c].y, v1, acc[c]);
                acc[c] = fmaf(w4[c].z, v2, acc[c]);
                acc[c] = fmaf(w4[c].w, v3, acc[c]);
            }
        }
    }
    #pragma unroll
    for (int c = 0; c < 8; ++c)
        out[((size_t)bh * DK + kk0 + c) * DV + t] = acc[c] * inv_scale;
}

// ---------------------------------------------------------------------------
extern "C" void kernel_launch(void* const* d_in, const int* in_sizes, int n_in,
                              void* d_out, int out_size, void* d_ws, size_t ws_size,
                              hipStream_t stream)
{
    const float* hs    = (const float*)d_in[0];
    const float* w_qkv = (const float*)d_in[1];
    const float* b_qkv = (const float*)d_in[2];
    const float* w_g   = (const float*)d_in[3];
    const float* b_g   = (const float*)d_in[4];
    const float* w_p   = (const float*)d_in[5];
    const float* b_p   = (const float*)d_in[6];
    float* out = (float*)d_out;

    // scratch layout (96 MB ws, plus d_out reuse):
    float*    qkv      = (float*)d_ws;                       // [0,64MB) fp32 qkv
    float*    normed   = qkv + (size_t)BT * QKV_LD;          // [64,96MB) fp32
    ushort_t* wqkv_t   = (ushort_t*)normed;                  // 8MB alias, dead after qkv GEMM
    ushort_t* hs_bf    = (ushort_t*)d_out;                   // out [0,8MB), dead before proj
    ushort_t* wg_t     = (ushort_t*)d_out + (size_t)4*1024*1024; // out [8,12MB), dead before proj
    ushort_t* wp_t     = (ushort_t*)((char*)d_ws + (size_t)16*1024*1024); // qkv [16,20MB), after retention/currkv
    ushort_t* gated_bf = (ushort_t*)qkv;                     // qkv [0,16MB), after retention/currkv

    // 1. bf16 conversions / weight transposes
    f32_to_bf16_kernel<<<dim3(BT * E_DIM / (256 * 8)), 256, 0, stream>>>(hs, hs_bf);
    transpose_w_kernel<<<dim3(128, 32), 256, 0, stream>>>(w_qkv, wqkv_t, E_DIM, 4096);
    transpose_w_kernel<<<dim3(64, 32), 256, 0, stream>>>(w_g, wg_t, E_DIM, V_DIM);

    // 2. qkv = hs @ w_qkv + b_qkv   (fp32 out for xpos/retention/currkv)
    gemm_bf16<0><<<dim3(32, 32), 256, 0, stream>>>(
        hs_bf, E_DIM, wqkv_t, E_DIM, b_qkv, qkv, QKV_LD, nullptr, 0, E_DIM / 32);

    // 3. xPos on q and k (in place, fp32)
    xpos_kernel<<<dim3(4, BT), 256, 0, stream>>>(qkv);

    // 4. retention + fused groupnorm -> normed (overwrites wqkv_t alias)
    retention_mfma<<<dim3(32, 16), 128, 0, stream>>>(qkv, normed);

    // 5. curr_kv -> second output region
    currkv_kernel<<<dim3(16, 16), 256, 0, stream>>>(qkv, out + (size_t)BT * E_DIM);

    // 6. w_p transpose into dead qkv region (after retention/currkv reads)
    transpose_w_kernel<<<dim3(32, 64), 256, 0, stream>>>(w_p, wp_t, V_DIM, E_DIM);

    // 7. gated = silu(hs @ w_g + b_g) * normed -> bf16 into dead qkv region
    gemm_bf16<1><<<dim3(16, 32), 256, 0, stream>>>(
        hs_bf, E_DIM, wg_t, E_DIM, b_g, gated_bf, V_DIM, normed, V_DIM, E_DIM / 32);

    // 8. proj = gated @ w_p + b_p -> first output region (overwrites hs_bf/wg_t)
    gemm_bf16<0><<<dim3(8, 32), 256, 0, stream>>>(
        gated_bf, V_DIM, wp_t, V_DIM, b_p, out, E_DIM, nullptr, 0, V_DIM / 32);
}

// Round 4
// 455.816 us; speedup vs baseline: 8.0988x; 1.3325x over previous
//
#include <hip/hip_runtime.h>
#include <math.h>

#define BT      4096
#define T_SEQ   2048
#define E_DIM   1024
#define V_DIM   2048
#define DK      128
#define DV      256
#define QKV_LD  4096

typedef unsigned short ushort_t;
typedef __attribute__((ext_vector_type(8)))  short bf16x8;
typedef __attribute__((ext_vector_type(4)))  unsigned short u16x4;
typedef __attribute__((ext_vector_type(16))) float f32x16;

__device__ __forceinline__ void decay_params(int h, float& ld, float& gamma) {
    const float s0 = -3.4657359027997265f;  // ln(1/32)
    const float e0 = -6.2383246250395092f;  // ln(1/512)
    float lin = s0 + (e0 - s0) * ((float)h * (1.0f / 7.0f));
    gamma = 1.0f - expf(lin);
    ld = logf(gamma);
}

__device__ __forceinline__ short f2bf(float f) {
    unsigned u = __float_as_uint(f);
    unsigned r = (u + 0x7fffu + ((u >> 16) & 1u)) >> 16;
    return (short)r;
}

__device__ __forceinline__ void async_copy16(void* lds, const void* g) {
    __builtin_amdgcn_global_load_lds(
        (const __attribute__((address_space(1))) unsigned int*)g,
        (__attribute__((address_space(3))) unsigned int*)lds, 16, 0, 0);
}

// ---------------------------------------------------------------------------
// fp32 -> bf16 elementwise
// ---------------------------------------------------------------------------
__global__ __launch_bounds__(256)
void f32_to_bf16_kernel(const float* __restrict__ in, ushort_t* __restrict__ out)
{
    int i = (blockIdx.x * 256 + threadIdx.x) * 8;
    float4 a = *(const float4*)&in[i];
    float4 b = *(const float4*)&in[i + 4];
    bf16x8 o;
    o[0] = f2bf(a.x); o[1] = f2bf(a.y); o[2] = f2bf(a.z); o[3] = f2bf(a.w);
    o[4] = f2bf(b.x); o[5] = f2bf(b.y); o[6] = f2bf(b.z); o[7] = f2bf(b.w);
    *(bf16x8*)&out[i] = o;
}

// ---------------------------------------------------------------------------
// W[K][N] fp32 -> Wt[N][K] bf16
// ---------------------------------------------------------------------------
__global__ __launch_bounds__(256)
void transpose_w_kernel(const float* __restrict__ W, ushort_t* __restrict__ Wt,
                        int K, int N)
{
    __shared__ float tile[32][33];
    const int k0 = blockIdx.y * 32, n0 = blockIdx.x * 32;
    const int t = threadIdx.x;
    const int r = t >> 3, c = (t & 7) * 4;
    float4 v = *(const float4*)&W[(size_t)(k0 + r) * N + n0 + c];
    tile[r][c] = v.x; tile[r][c + 1] = v.y; tile[r][c + 2] = v.z; tile[r][c + 3] = v.w;
    __syncthreads();
    u16x4 o;
    o[0] = (ushort_t)f2bf(tile[c][r]);
    o[1] = (ushort_t)f2bf(tile[c + 1][r]);
    o[2] = (ushort_t)f2bf(tile[c + 2][r]);
    o[3] = (ushort_t)f2bf(tile[c + 3][r]);
    *(u16x4*)&Wt[(size_t)(n0 + r) * K + k0 + c] = o;
}

// ---------------------------------------------------------------------------
// bf16 MFMA GEMM (unchanged from round 3, verified)
// ---------------------------------------------------------------------------
template<int EPI>
__global__ __launch_bounds__(256)
void gemm_bf16(const ushort_t* __restrict__ A, int lda,
               const ushort_t* __restrict__ Bt, int ldb,
               const float* __restrict__ bias,
               void* __restrict__ Cv, int ldc,
               const float* __restrict__ extra, int lde,
               int nkt)
{
    __shared__ ushort_t As[128 * 32];
    __shared__ ushort_t Bs[128 * 32];

    const int tid = threadIdx.x;
    const int w  = tid >> 6, l = tid & 63;
    const int lc = l & 31, q = l >> 5;
    const int wr = w >> 1, wc = w & 1;
    const int m0 = blockIdx.y * 128, n0 = blockIdx.x * 128;

    const int r0 = tid >> 2,         kc0 = (tid & 3) ^ ((r0 >> 1) & 3);
    const int r1 = (256 + tid) >> 2, kc1 = (tid & 3) ^ ((r1 >> 1) & 3);
    const ushort_t* gA0 = A  + (size_t)(m0 + r0) * lda + kc0 * 8;
    const ushort_t* gA1 = A  + (size_t)(m0 + r1) * lda + kc1 * 8;
    const ushort_t* gB0 = Bt + (size_t)(n0 + r0) * ldb + kc0 * 8;
    const ushort_t* gB1 = Bt + (size_t)(n0 + r1) * ldb + kc1 * 8;
    ushort_t* lA0 = &As[(w * 64) * 8];
    ushort_t* lA1 = &As[(256 + w * 64) * 8];
    ushort_t* lB0 = &Bs[(w * 64) * 8];
    ushort_t* lB1 = &Bs[(256 + w * 64) * 8];

    const int sl = (lc >> 1) & 3;
    const bf16x8* apt[2][2];
    const bf16x8* bpt[2][2];
    #pragma unroll
    for (int mi = 0; mi < 2; ++mi)
        #pragma unroll
        for (int ks = 0; ks < 2; ++ks) {
            const int kc = ks * 2 + q;
            const int mrow = wr * 64 + mi * 32 + lc;
            const int nrow = wc * 64 + mi * 32 + lc;
            apt[mi][ks] = (const bf16x8*)&As[(mrow * 4 + (kc ^ sl)) * 8];
            bpt[mi][ks] = (const bf16x8*)&Bs[(nrow * 4 + (kc ^ sl)) * 8];
        }

    f32x16 acc[2][2];
    #pragma unroll
    for (int mi = 0; mi < 2; ++mi)
        #pragma unroll
        for (int ni = 0; ni < 2; ++ni)
            #pragma unroll
            for (int e = 0; e < 16; ++e) acc[mi][ni][e] = 0.0f;

    for (int kt = 0; kt < nkt; ++kt) {
        async_copy16(lA0, gA0); async_copy16(lA1, gA1);
        async_copy16(lB0, gB0); async_copy16(lB1, gB1);
        gA0 += 32; gA1 += 32; gB0 += 32; gB1 += 32;
        __syncthreads();

        bf16x8 a[2][2], b[2][2];
        #pragma unroll
        for (int mi = 0; mi < 2; ++mi)
            #pragma unroll
            for (int ks = 0; ks < 2; ++ks) {
                a[mi][ks] = *apt[mi][ks];
                b[mi][ks] = *bpt[mi][ks];
            }
        #pragma unroll
        for (int ks = 0; ks < 2; ++ks)
            #pragma unroll
            for (int mi = 0; mi < 2; ++mi)
                #pragma unroll
                for (int ni = 0; ni < 2; ++ni)
                    acc[mi][ni] = __builtin_amdgcn_mfma_f32_32x32x16_bf16(
                        a[mi][ks], b[ni][ks], acc[mi][ni], 0, 0, 0);
        __syncthreads();
    }

    #pragma unroll
    for (int ni = 0; ni < 2; ++ni) {
        const int col = n0 + wc * 64 + ni * 32 + lc;
        const float bb = bias[col];
        #pragma unroll
        for (int mi = 0; mi < 2; ++mi) {
            #pragma unroll
            for (int r = 0; r < 16; ++r) {
                const int row = m0 + wr * 64 + mi * 32 + (r & 3) + 8 * (r >> 2) + 4 * q;
                float val = acc[mi][ni][r] + bb;
                if (EPI == 0) {
                    ((float*)Cv)[(size_t)row * ldc + col] = val;
                } else {
                    const float e = extra[(size_t)row * lde + col];
                    val = val / (1.0f + expf(-val)) * e;
                    ((ushort_t*)Cv)[(size_t)row * ldc + col] = (ushort_t)f2bf(val);
                }
            }
        }
    }
}

// ---------------------------------------------------------------------------
// q/k prep: xpos rotation + gamma^{+-(t&31)} pre-scale + bf16, head-major
// layout [bh][T][128]. One block per (b,t) row; threads<128 -> q, >=128 -> k.
// ---------------------------------------------------------------------------
__global__ __launch_bounds__(256)
void qk_prep(const float* __restrict__ qkv,
             ushort_t* __restrict__ qh, ushort_t* __restrict__ kh)
{
    const int row = blockIdx.x;
    const int t = threadIdx.x;
    const int b = row >> 11, trow = row & (T_SEQ - 1);
    const bool isK = t >= 128;
    const int col0 = (t & 127) * 8;
    const int h = col0 >> 7, d = col0 & 127;

    float ld, gamma;
    decay_params(h, ld, gamma);
    const float gsc = expf(isK ? -ld * (float)(trow & 31) : ld * (float)(trow & 31));

    const float* src = qkv + (size_t)row * QKV_LD + (isK ? E_DIM : 0) + col0;
    float4 x0 = *(const float4*)src;
    float4 x1 = *(const float4*)(src + 4);
    float xv[8] = {x0.x, x0.y, x0.z, x0.w, x1.x, x1.y, x1.z, x1.w};

    bf16x8 o;
    #pragma unroll
    for (int pi = 0; pi < 4; ++pi) {
        const int ip = col0 / 2 + pi;
        float sv = (2.0f * (float)ip + 409.6f) * (1.0f / 1433.6f);
        float sc = powf(sv, (float)trow * (1.0f / 512.0f));
        if (isK) sc = 1.0f / sc;
        float invf = powf(10000.0f, -(float)ip * (1.0f / 512.0f));
        float sn, cs;
        sincosf((float)trow * invf, &sn, &cs);
        float c = cs * sc * gsc, s = sn * sc * gsc;
        float a = xv[2 * pi], bb = xv[2 * pi + 1];
        o[2 * pi]     = f2bf(a * c - bb * s);
        o[2 * pi + 1] = f2bf(bb * c + a * s);
    }
    ushort_t* dst = (isK ? kh : qh) + ((size_t)(b * 8 + h) * T_SEQ + trow) * 128 + d;
    *(bf16x8*)dst = o;
}

// ---------------------------------------------------------------------------
// V transpose: qkv v-section [b][t][h*256+v] fp32 -> vt [bh][256][T] bf16
// ---------------------------------------------------------------------------
__global__ __launch_bounds__(256)
void v_transpose(const float* __restrict__ qkv, ushort_t* __restrict__ vt)
{
    __shared__ float tile[32][33];
    const int j0 = blockIdx.x * 32;
    const int zz = blockIdx.y;                 // bh*8 + vtile
    const int bh = zz >> 3, v0 = (zz & 7) * 32;
    const int b = bh >> 3, h = bh & 7;
    const int t = threadIdx.x;
    const int r = t >> 3, c = (t & 7) * 4;

    float4 x = *(const float4*)(qkv + (size_t)(b * T_SEQ + j0 + r) * QKV_LD
                                + 2 * E_DIM + h * DV + v0 + c);
    tile[r][c] = x.x; tile[r][c+1] = x.y; tile[r][c+2] = x.z; tile[r][c+3] = x.w;
    __syncthreads();
    u16x4 o;
    o[0] = (ushort_t)f2bf(tile[c][r]);
    o[1] = (ushort_t)f2bf(tile[c + 1][r]);
    o[2] = (ushort_t)f2bf(tile[c + 2][r]);
    o[3] = (ushort_t)f2bf(tile[c + 3][r]);
    *(u16x4*)&vt[((size_t)bh * 256 + v0 + r) * T_SEQ + j0 + c] = o;
}

// ---------------------------------------------------------------------------
// ktw prep: k-section + xpos(downscale) + gamma^{T-1-j} weight, transposed
// to [bh][128][T] bf16 (for curr_kv GEMM).
// ---------------------------------------------------------------------------
__global__ __launch_bounds__(256)
void ktw_prep(const float* __restrict__ qkv, ushort_t* __restrict__ ktw)
{
    __shared__ float tile[32][33];
    const int j0 = blockIdx.x * 32;
    const int zz = blockIdx.y;                 // bh*4 + kktile
    const int bh = zz >> 2, kk0 = (zz & 3) * 32;
    const int b = bh >> 3, h = bh & 7;
    const int t = threadIdx.x;
    const int r = t >> 3, c = (t & 7) * 4;
    const int j = j0 + r;

    float ld, gamma;
    decay_params(h, ld, gamma);
    const float w = expf(ld * (float)(T_SEQ - 1 - j));

    float4 x = *(const float4*)(qkv + (size_t)(b * T_SEQ + j) * QKV_LD
                                + E_DIM + h * DK + kk0 + c);
    float xv[4] = {x.x, x.y, x.z, x.w};
    #pragma unroll
    for (int pi = 0; pi < 2; ++pi) {
        const int ip = (h * 128 + kk0 + c) / 2 + pi;
        float sv = (2.0f * (float)ip + 409.6f) * (1.0f / 1433.6f);
        float sc = 1.0f / powf(sv, (float)j * (1.0f / 512.0f));
        float invf = powf(10000.0f, -(float)ip * (1.0f / 512.0f));
        float sn, cs;
        sincosf((float)j * invf, &sn, &cs);
        float ce = cs * sc * w, se = sn * sc * w;
        float a = xv[2 * pi], bb = xv[2 * pi + 1];
        tile[r][c + 2 * pi]     = a * ce - bb * se;
        tile[r][c + 2 * pi + 1] = bb * ce + a * se;
    }
    __syncthreads();
    u16x4 o;
    o[0] = (ushort_t)f2bf(tile[c][r]);
    o[1] = (ushort_t)f2bf(tile[c + 1][r]);
    o[2] = (ushort_t)f2bf(tile[c + 2][r]);
    o[3] = (ushort_t)f2bf(tile[c + 3][r]);
    *(u16x4*)&ktw[((size_t)bh * 128 + kk0 + r) * T_SEQ + j0 + c] = o;
}

// ---------------------------------------------------------------------------
// Retention v2: preprocessed bf16 inputs, global_load_lds staging,
// paired i-tiles (p, 63-p) for perfect balance. Block = 128 thr = 2 waves.
// ---------------------------------------------------------------------------
__global__ __launch_bounds__(128)
void retention_mfma2(const ushort_t* __restrict__ qh,
                     const ushort_t* __restrict__ kh,
                     const ushort_t* __restrict__ vt,
                     float* __restrict__ normed)
{
    __shared__ ushort_t Ks[32 * 128];   // [j][d], chunk-swizzled (c ^ (j&7))
    __shared__ ushort_t Vt[256 * 32];   // [v][j], chunk-swizzled (c ^ ((v>>1)&3))

    const int p  = blockIdx.x;              // 0..31 (pair id; big staging first)
    const int bh = blockIdx.y;
    const int h  = bh & 7;
    const int tid = threadIdx.x;
    const int w  = tid >> 6;
    const int l  = tid & 63;
    const int lc = l & 31;
    const int q  = l >> 5;
    const int wsel = tid & 64;              // wave-uniform 0/64
    const int it = (w == 0) ? p : (63 - p);
    const int i0 = it * 32;
    const size_t bhT = (size_t)bh * T_SEQ;

    float ld, gamma;
    decay_params(h, ld, gamma);

    // Q fragments (pre-scaled, pre-rotated): row i0+lc, chunks c*16+q*8
    bf16x8 qf[8];
    {
        const ushort_t* qp = qh + (bhT + i0 + lc) * 128 + q * 8;
        #pragma unroll
        for (int c = 0; c < 8; ++c)
            qf[c] = *(const bf16x8*)(qp + c * 16);
    }

    f32x16 acc[8];
    #pragma unroll
    for (int vg = 0; vg < 8; ++vg)
        #pragma unroll
        for (int e = 0; e < 16; ++e) acc[vg][e] = 0.0f;

    const int njt = 64 - p;
    for (int jt = 0; jt < njt; ++jt) {
        const int j0 = jt * 32;
        __syncthreads();

        // ---- stage K tile (8KB): LDS chunk ci holds global chunk (ci&7)^(r&7)
        #pragma unroll
        for (int s = 0; s < 4; ++s) {
            const int ci = s * 128 + tid;
            const int r = ci >> 3;
            const int c = (ci & 7) ^ (r & 7);
            async_copy16((char*)Ks + (size_t)(s * 128 + wsel) * 16,
                         kh + (bhT + j0 + r) * 128 + c * 8);
        }
        // ---- stage V^T tile (16KB): chunk ci -> row ci>>2, global chunk (ci&3)^((r>>1)&3)
        #pragma unroll
        for (int s = 0; s < 8; ++s) {
            const int ci = s * 128 + tid;
            const int r = ci >> 2;
            const int c = (ci & 3) ^ ((r >> 1) & 3);
            async_copy16((char*)Vt + (size_t)(s * 128 + wsel) * 16,
                         vt + ((size_t)bh * 256 + r) * T_SEQ + j0 + c * 8);
        }
        __syncthreads();

        if (jt > it) continue;   // wave-uniform

        // ---- S^T = K . Q^T
        f32x16 s;
        #pragma unroll
        for (int e = 0; e < 16; ++e) s[e] = 0.0f;
        #pragma unroll
        for (int c = 0; c < 8; ++c) {
            const int pos = (2 * c + q) ^ (lc & 7);
            bf16x8 ka = *(const bf16x8*)((char*)Ks + lc * 256 + pos * 16);
            s = __builtin_amdgcn_mfma_f32_32x32x16_bf16(ka, qf[c], s, 0, 0, 0);
        }

        const float csc = expf(ld * (float)(i0 - j0));
        float sv[16];
        #pragma unroll
        for (int r = 0; r < 16; ++r) {
            float val = s[r] * csc;
            if (jt == it) {
                int jr_ = (r & 3) + 8 * (r >> 2) + 4 * q;
                val = (jr_ <= lc) ? val : 0.0f;
            }
            sv[r] = val;
        }

        // ---- C-layout -> A-operand fragments (shfl across half-waves)
        bf16x8 pa0, pa1;
        #pragma unroll
        for (int e = 0; e < 4; ++e) {
            float t1 = __shfl_xor(sv[e + 4], 32);
            float t0 = __shfl_xor(sv[e], 32);
            pa0[e]     = f2bf(q ? t1 : sv[e]);
            pa0[e + 4] = f2bf(q ? sv[e + 4] : t0);
            float t3 = __shfl_xor(sv[e + 12], 32);
            float t2 = __shfl_xor(sv[e + 8], 32);
            pa1[e]     = f2bf(q ? t3 : sv[e + 8]);
            pa1[e + 4] = f2bf(q ? sv[e + 12] : t2);
        }

        // ---- O += P . V
        const int sw = (lc >> 1) & 3;
        #pragma unroll
        for (int vg = 0; vg < 8; ++vg) {
            const char* vb = (const char*)Vt + (vg * 32 + lc) * 64;
            bf16x8 vb0 = *(const bf16x8*)(vb + ((q ^ sw) * 16));
            bf16x8 vb1 = *(const bf16x8*)(vb + (((2 + q) ^ sw) * 16));
            acc[vg] = __builtin_amdgcn_mfma_f32_32x32x16_bf16(pa0, vb0, acc[vg], 0, 0, 0);
            acc[vg] = __builtin_amdgcn_mfma_f32_32x32x16_bf16(pa1, vb1, acc[vg], 0, 0, 0);
        }
    }

    // ---- epilogue: row scale + fused groupnorm + store
    #pragma unroll
    for (int r = 0; r < 16; ++r) {
        const int il = (r & 3) + 8 * (r >> 2) + 4 * q;
        const int i  = i0 + il;
        float denom = (1.0f - expf(ld * (float)(i + 1))) / (1.0f - gamma);
        float fs = 0.08838834764831845f * rsqrtf(denom);
        float vals[8];
        float a1 = 0.0f, a2 = 0.0f;
        #pragma unroll
        for (int vg = 0; vg < 8; ++vg) {
            float x = acc[vg][r] * fs;
            vals[vg] = x;
            a1 += x; a2 += x * x;
        }
        a1 += __shfl_xor(a1, 1);  a2 += __shfl_xor(a2, 1);
        a1 += __shfl_xor(a1, 2);  a2 += __shfl_xor(a2, 2);
        a1 += __shfl_xor(a1, 4);  a2 += __shfl_xor(a2, 4);
        a1 += __shfl_xor(a1, 8);  a2 += __shfl_xor(a2, 8);
        a1 += __shfl_xor(a1, 16); a2 += __shfl_xor(a2, 16);
        float mu = a1 * (1.0f / 256.0f);
        float var = a2 * (1.0f / 256.0f) - mu * mu;
        float rs = rsqrtf(var + 1e-5f);
        float* op = normed + (bhT / T_SEQ * 0 + (size_t)((bh >> 3) * T_SEQ + i)) * V_DIM + h * DV + lc;
        #pragma unroll
        for (int vg = 0; vg < 8; ++vg)
            op[vg * 32] = (vals[vg] - mu) * rs;
    }
}

// ---------------------------------------------------------------------------
// curr_kv as bf16 MFMA GEMM: out[bh][kk][vv] = sum_j ktw[kk][j] * vt[vv][j]
// 512 single-wave blocks; operands read straight from global (L2-resident).
// ---------------------------------------------------------------------------
__global__ __launch_bounds__(64)
void currkv_mfma(const ushort_t* __restrict__ ktw, const ushort_t* __restrict__ vt,
                 float* __restrict__ out)
{
    const int tile = blockIdx.x;            // 0..31: kk-tile(4) x vv-tile(8)
    const int bh = blockIdx.y;
    const int kk0 = (tile >> 3) * 32, vv0 = (tile & 7) * 32;
    const int l = threadIdx.x, lc = l & 31, q = l >> 5;

    const ushort_t* ar = ktw + ((size_t)bh * 128 + kk0 + lc) * T_SEQ + q * 8;
    const ushort_t* br = vt  + ((size_t)bh * 256 + vv0 + lc) * T_SEQ + q * 8;

    f32x16 acc;
    #pragma unroll
    for (int e = 0; e < 16; ++e) acc[e] = 0.0f;

    for (int j = 0; j < T_SEQ; j += 64) {
        bf16x8 a[4], b[4];
        #pragma unroll
        for (int u = 0; u < 4; ++u) {
            a[u] = *(const bf16x8*)(ar + j + u * 16);
            b[u] = *(const bf16x8*)(br + j + u * 16);
        }
        #pragma unroll
        for (int u = 0; u < 4; ++u)
            acc = __builtin_amdgcn_mfma_f32_32x32x16_bf16(a[u], b[u], acc, 0, 0, 0);
    }

    float ld, gamma;
    decay_params(bh & 7, ld, gamma);
    const float inv_scale = rsqrtf((1.0f - expf(ld * (float)T_SEQ)) / (1.0f - gamma));

    #pragma unroll
    for (int r = 0; r < 16; ++r) {
        const int kk = kk0 + (r & 3) + 8 * (r >> 2) + 4 * q;
        out[((size_t)bh * 128 + kk) * 256 + vv0 + lc] = acc[r] * inv_scale;
    }
}

// ---------------------------------------------------------------------------
extern "C" void kernel_launch(void* const* d_in, const int* in_sizes, int n_in,
                              void* d_out, int out_size, void* d_ws, size_t ws_size,
                              hipStream_t stream)
{
    const float* hs    = (const float*)d_in[0];
    const float* w_qkv = (const float*)d_in[1];
    const float* b_qkv = (const float*)d_in[2];
    const float* w_g   = (const float*)d_in[3];
    const float* b_g   = (const float*)d_in[4];
    const float* w_p   = (const float*)d_in[5];
    const float* b_p   = (const float*)d_in[6];
    float* out = (float*)d_out;

    const size_t MB = 1024 * 1024;
    // ws (96MB):
    float*    qkv      = (float*)d_ws;                          // [0,64) fp32, dead after preps
    float*    normed   = (float*)d_ws;                          // [0,32) after qkv dead
    ushort_t* gated_bf = (ushort_t*)((char*)d_ws + 32 * MB);    // [32,48)
    ushort_t* hs_bf2   = (ushort_t*)((char*)d_ws + 48 * MB);    // [48,56)
    ushort_t* wg_t     = (ushort_t*)((char*)d_ws + 56 * MB);    // [56,60)
    ushort_t* wp_t     = (ushort_t*)((char*)d_ws + 60 * MB);    // [60,64)
    ushort_t* qh       = (ushort_t*)((char*)d_ws + 64 * MB);    // [64,72)
    ushort_t* vt       = (ushort_t*)((char*)d_ws + 72 * MB);    // [72,88)
    ushort_t* wqkv_t   = (ushort_t*)((char*)d_ws + 88 * MB);    // [88,96)
    // d_out (18.9MB): kh[0,8), ktw[8,16) both dead before proj writes [0,16.78)
    ushort_t* hs_bf1   = (ushort_t*)d_out;                      // dead after qkv GEMM
    ushort_t* kh       = (ushort_t*)d_out;
    ushort_t* ktw      = (ushort_t*)((char*)d_out + 8 * MB);
    float*    ckv_out  = out + (size_t)BT * E_DIM;

    // 1. hs -> bf16 (into d_out scratch), w_qkv transpose
    f32_to_bf16_kernel<<<dim3(2048), 256, 0, stream>>>(hs, hs_bf1);
    transpose_w_kernel<<<dim3(128, 32), 256, 0, stream>>>(w_qkv, wqkv_t, E_DIM, 4096);

    // 2. qkv = hs @ w_qkv + b_qkv (fp32)
    gemm_bf16<0><<<dim3(32, 32), 256, 0, stream>>>(
        hs_bf1, E_DIM, wqkv_t, E_DIM, b_qkv, qkv, QKV_LD, nullptr, 0, E_DIM / 32);

    // 3. preps: q/k (xpos+scale+bf16), v transpose, weighted-k transpose
    qk_prep<<<dim3(BT), 256, 0, stream>>>(qkv, qh, kh);
    v_transpose<<<dim3(64, 128), 256, 0, stream>>>(qkv, vt);
    ktw_prep<<<dim3(64, 64), 256, 0, stream>>>(qkv, ktw);

    // 4. retention + groupnorm -> normed (overwrites dead qkv region)
    retention_mfma2<<<dim3(32, 16), 128, 0, stream>>>(qh, kh, vt, normed);

    // 5. curr_kv
    currkv_mfma<<<dim3(32, 16), 64, 0, stream>>>(ktw, vt, ckv_out);

    // 6. late conversions (regions free now)
    f32_to_bf16_kernel<<<dim3(2048), 256, 0, stream>>>(hs, hs_bf2);
    transpose_w_kernel<<<dim3(64, 32), 256, 0, stream>>>(w_g, wg_t, E_DIM, V_DIM);
    transpose_w_kernel<<<dim3(32, 64), 256, 0, stream>>>(w_p, wp_t, V_DIM, E_DIM);

    // 7. gated = silu(hs @ w_g + b_g) * normed -> bf16
    gemm_bf16<1><<<dim3(16, 32), 256, 0, stream>>>(
        hs_bf2, E_DIM, wg_t, E_DIM, b_g, gated_bf, V_DIM, normed, V_DIM, E_DIM / 32);

    // 8. proj = gated @ w_p + b_p (overwrites kh/ktw)
    gemm_bf16<0><<<dim3(8, 32), 256, 0, stream>>>(
        gated_bf, V_DIM, wp_t, V_DIM, b_p, out, E_DIM, nullptr, 0, V_DIM / 32);
}

// Round 5
// 394.078 us; speedup vs baseline: 9.3676x; 1.1567x over previous
//
#include <hip/hip_runtime.h>
#include <math.h>

#define BT      4096
#define T_SEQ   2048
#define E_DIM   1024
#define V_DIM   2048
#define DK      128
#define DV      256
#define QKV_LD  4096

typedef unsigned short ushort_t;
typedef __attribute__((ext_vector_type(8)))  short bf16x8;
typedef __attribute__((ext_vector_type(4)))  unsigned short u16x4;
typedef __attribute__((ext_vector_type(16))) float f32x16;

__device__ __forceinline__ void decay_params(int h, float& ld, float& gamma) {
    const float s0 = -3.4657359027997265f;  // ln(1/32)
    const float e0 = -6.2383246250395092f;  // ln(1/512)
    float lin = s0 + (e0 - s0) * ((float)h * (1.0f / 7.0f));
    gamma = 1.0f - expf(lin);
    ld = logf(gamma);
}

__device__ __forceinline__ short f2bf(float f) {
    unsigned u = __float_as_uint(f);
    unsigned r = (u + 0x7fffu + ((u >> 16) & 1u)) >> 16;
    return (short)r;
}
__device__ __forceinline__ float bf2f(ushort_t u) {
    return __uint_as_float((unsigned)u << 16);
}

__device__ __forceinline__ void async_copy16(void* lds, const void* g) {
    __builtin_amdgcn_global_load_lds(
        (const __attribute__((address_space(1))) unsigned int*)g,
        (__attribute__((address_space(3))) unsigned int*)lds, 16, 0, 0);
}

// ---------------------------------------------------------------------------
// fp32 -> bf16 elementwise
// ---------------------------------------------------------------------------
__global__ __launch_bounds__(256)
void f32_to_bf16_kernel(const float* __restrict__ in, ushort_t* __restrict__ out)
{
    int i = (blockIdx.x * 256 + threadIdx.x) * 8;
    float4 a = *(const float4*)&in[i];
    float4 b = *(const float4*)&in[i + 4];
    bf16x8 o;
    o[0] = f2bf(a.x); o[1] = f2bf(a.y); o[2] = f2bf(a.z); o[3] = f2bf(a.w);
    o[4] = f2bf(b.x); o[5] = f2bf(b.y); o[6] = f2bf(b.z); o[7] = f2bf(b.w);
    *(bf16x8*)&out[i] = o;
}

// ---------------------------------------------------------------------------
// W[K][N] fp32 -> Wt[N][K] bf16
// ---------------------------------------------------------------------------
__global__ __launch_bounds__(256)
void transpose_w_kernel(const float* __restrict__ W, ushort_t* __restrict__ Wt,
                        int K, int N)
{
    __shared__ float tile[32][33];
    const int k0 = blockIdx.y * 32, n0 = blockIdx.x * 32;
    const int t = threadIdx.x;
    const int r = t >> 3, c = (t & 7) * 4;
    float4 v = *(const float4*)&W[(size_t)(k0 + r) * N + n0 + c];
    tile[r][c] = v.x; tile[r][c + 1] = v.y; tile[r][c + 2] = v.z; tile[r][c + 3] = v.w;
    __syncthreads();
    u16x4 o;
    o[0] = (ushort_t)f2bf(tile[c][r]);
    o[1] = (ushort_t)f2bf(tile[c + 1][r]);
    o[2] = (ushort_t)f2bf(tile[c + 2][r]);
    o[3] = (ushort_t)f2bf(tile[c + 3][r]);
    *(u16x4*)&Wt[(size_t)(n0 + r) * K + k0 + c] = o;
}

// ---------------------------------------------------------------------------
// bf16 MFMA GEMM (unchanged, verified)
// ---------------------------------------------------------------------------
template<int EPI>
__global__ __launch_bounds__(256)
void gemm_bf16(const ushort_t* __restrict__ A, int lda,
               const ushort_t* __restrict__ Bt, int ldb,
               const float* __restrict__ bias,
               void* __restrict__ Cv, int ldc,
               const float* __restrict__ extra, int lde,
               int nkt)
{
    __shared__ ushort_t As[128 * 32];
    __shared__ ushort_t Bs[128 * 32];

    const int tid = threadIdx.x;
    const int w  = tid >> 6, l = tid & 63;
    const int lc = l & 31, q = l >> 5;
    const int wr = w >> 1, wc = w & 1;
    const int m0 = blockIdx.y * 128, n0 = blockIdx.x * 128;

    const int r0 = tid >> 2,         kc0 = (tid & 3) ^ ((r0 >> 1) & 3);
    const int r1 = (256 + tid) >> 2, kc1 = (tid & 3) ^ ((r1 >> 1) & 3);
    const ushort_t* gA0 = A  + (size_t)(m0 + r0) * lda + kc0 * 8;
    const ushort_t* gA1 = A  + (size_t)(m0 + r1) * lda + kc1 * 8;
    const ushort_t* gB0 = Bt + (size_t)(n0 + r0) * ldb + kc0 * 8;
    const ushort_t* gB1 = Bt + (size_t)(n0 + r1) * ldb + kc1 * 8;
    ushort_t* lA0 = &As[(w * 64) * 8];
    ushort_t* lA1 = &As[(256 + w * 64) * 8];
    ushort_t* lB0 = &Bs[(w * 64) * 8];
    ushort_t* lB1 = &Bs[(256 + w * 64) * 8];

    const int sl = (lc >> 1) & 3;
    const bf16x8* apt[2][2];
    const bf16x8* bpt[2][2];
    #pragma unroll
    for (int mi = 0; mi < 2; ++mi)
        #pragma unroll
        for (int ks = 0; ks < 2; ++ks) {
            const int kc = ks * 2 + q;
            const int mrow = wr * 64 + mi * 32 + lc;
            const int nrow = wc * 64 + mi * 32 + lc;
            apt[mi][ks] = (const bf16x8*)&As[(mrow * 4 + (kc ^ sl)) * 8];
            bpt[mi][ks] = (const bf16x8*)&Bs[(nrow * 4 + (kc ^ sl)) * 8];
        }

    f32x16 acc[2][2];
    #pragma unroll
    for (int mi = 0; mi < 2; ++mi)
        #pragma unroll
        for (int ni = 0; ni < 2; ++ni)
            #pragma unroll
            for (int e = 0; e < 16; ++e) acc[mi][ni][e] = 0.0f;

    for (int kt = 0; kt < nkt; ++kt) {
        async_copy16(lA0, gA0); async_copy16(lA1, gA1);
        async_copy16(lB0, gB0); async_copy16(lB1, gB1);
        gA0 += 32; gA1 += 32; gB0 += 32; gB1 += 32;
        __syncthreads();

        bf16x8 a[2][2], b[2][2];
        #pragma unroll
        for (int mi = 0; mi < 2; ++mi)
            #pragma unroll
            for (int ks = 0; ks < 2; ++ks) {
                a[mi][ks] = *apt[mi][ks];
                b[mi][ks] = *bpt[mi][ks];
            }
        #pragma unroll
        for (int ks = 0; ks < 2; ++ks)
            #pragma unroll
            for (int mi = 0; mi < 2; ++mi)
                #pragma unroll
                for (int ni = 0; ni < 2; ++ni)
                    acc[mi][ni] = __builtin_amdgcn_mfma_f32_32x32x16_bf16(
                        a[mi][ks], b[ni][ks], acc[mi][ni], 0, 0, 0);
        __syncthreads();
    }

    #pragma unroll
    for (int ni = 0; ni < 2; ++ni) {
        const int col = n0 + wc * 64 + ni * 32 + lc;
        const float bb = bias[col];
        #pragma unroll
        for (int mi = 0; mi < 2; ++mi) {
            #pragma unroll
            for (int r = 0; r < 16; ++r) {
                const int row = m0 + wr * 64 + mi * 32 + (r & 3) + 8 * (r >> 2) + 4 * q;
                float val = acc[mi][ni][r] + bb;
                if (EPI == 0) {
                    ((float*)Cv)[(size_t)row * ldc + col] = val;
                } else {
                    const float e = extra[(size_t)row * lde + col];
                    val = val / (1.0f + expf(-val)) * e;
                    ((ushort_t*)Cv)[(size_t)row * ldc + col] = (ushort_t)f2bf(val);
                }
            }
        }
    }
}

// ---------------------------------------------------------------------------
// q/k prep: xpos + gamma^{+-(t&63)} pre-scale (mod-64 for chunked scheme),
// bf16 head-major [bh][T][128].
// ---------------------------------------------------------------------------
__global__ __launch_bounds__(256)
void qk_prep(const float* __restrict__ qkv,
             ushort_t* __restrict__ qh, ushort_t* __restrict__ kh)
{
    const int row = blockIdx.x;
    const int t = threadIdx.x;
    const int b = row >> 11, trow = row & (T_SEQ - 1);
    const bool isK = t >= 128;
    const int col0 = (t & 127) * 8;
    const int h = col0 >> 7, d = col0 & 127;

    float ld, gamma;
    decay_params(h, ld, gamma);
    const float gsc = expf(isK ? -ld * (float)(trow & 63) : ld * (float)(trow & 63));

    const float* src = qkv + (size_t)row * QKV_LD + (isK ? E_DIM : 0) + col0;
    float4 x0 = *(const float4*)src;
    float4 x1 = *(const float4*)(src + 4);
    float xv[8] = {x0.x, x0.y, x0.z, x0.w, x1.x, x1.y, x1.z, x1.w};

    bf16x8 o;
    #pragma unroll
    for (int pi = 0; pi < 4; ++pi) {
        const int ip = col0 / 2 + pi;
        float sv = (2.0f * (float)ip + 409.6f) * (1.0f / 1433.6f);
        float sc = powf(sv, (float)trow * (1.0f / 512.0f));
        if (isK) sc = 1.0f / sc;
        float invf = powf(10000.0f, -(float)ip * (1.0f / 512.0f));
        float sn, cs;
        sincosf((float)trow * invf, &sn, &cs);
        float c = cs * sc * gsc, s = sn * sc * gsc;
        float a = xv[2 * pi], bb = xv[2 * pi + 1];
        o[2 * pi]     = f2bf(a * c - bb * s);
        o[2 * pi + 1] = f2bf(bb * c + a * s);
    }
    ushort_t* dst = (isK ? kh : qh) + ((size_t)(b * 8 + h) * T_SEQ + trow) * 128 + d;
    *(bf16x8*)dst = o;
}

// ---------------------------------------------------------------------------
// V transpose: fp32 v-section -> vt [bh][256][T] bf16
// ---------------------------------------------------------------------------
__global__ __launch_bounds__(256)
void v_transpose(const float* __restrict__ qkv, ushort_t* __restrict__ vt)
{
    __shared__ float tile[32][33];
    const int j0 = blockIdx.x * 32;
    const int zz = blockIdx.y;
    const int bh = zz >> 3, v0 = (zz & 7) * 32;
    const int b = bh >> 3, h = bh & 7;
    const int t = threadIdx.x;
    const int r = t >> 3, c = (t & 7) * 4;

    float4 x = *(const float4*)(qkv + (size_t)(b * T_SEQ + j0 + r) * QKV_LD
                                + 2 * E_DIM + h * DV + v0 + c);
    tile[r][c] = x.x; tile[r][c+1] = x.y; tile[r][c+2] = x.z; tile[r][c+3] = x.w;
    __syncthreads();
    u16x4 o;
    o[0] = (ushort_t)f2bf(tile[c][r]);
    o[1] = (ushort_t)f2bf(tile[c + 1][r]);
    o[2] = (ushort_t)f2bf(tile[c + 2][r]);
    o[3] = (ushort_t)f2bf(tile[c + 3][r]);
    *(u16x4*)&vt[((size_t)bh * 256 + v0 + r) * T_SEQ + j0 + c] = o;
}

// ---------------------------------------------------------------------------
// kt2 prep: xpos(downscale) k, weighted by gamma^{63-(j&63)}, transposed
// to [bh][128][T] bf16 (B-operand for per-chunk K^T V).
// ---------------------------------------------------------------------------
__global__ __launch_bounds__(256)
void kt2_prep(const float* __restrict__ qkv, ushort_t* __restrict__ kt2)
{
    __shared__ float tile[32][33];
    const int j0 = blockIdx.x * 32;
    const int zz = blockIdx.y;
    const int bh = zz >> 2, kk0 = (zz & 3) * 32;
    const int b = bh >> 3, h = bh & 7;
    const int t = threadIdx.x;
    const int r = t >> 3, c = (t & 7) * 4;
    const int j = j0 + r;

    float ld, gamma;
    decay_params(h, ld, gamma);
    const float w = expf(ld * (float)(63 - (j & 63)));

    float4 x = *(const float4*)(qkv + (size_t)(b * T_SEQ + j) * QKV_LD
                                + E_DIM + h * DK + kk0 + c);
    float xv[4] = {x.x, x.y, x.z, x.w};
    #pragma unroll
    for (int pi = 0; pi < 2; ++pi) {
        const int ip = (h * 128 + kk0 + c) / 2 + pi;
        float sv = (2.0f * (float)ip + 409.6f) * (1.0f / 1433.6f);
        float sc = 1.0f / powf(sv, (float)j * (1.0f / 512.0f));
        float invf = powf(10000.0f, -(float)ip * (1.0f / 512.0f));
        float sn, cs;
        sincosf((float)j * invf, &sn, &cs);
        float ce = cs * sc * w, se = sn * sc * w;
        float a = xv[2 * pi], bb = xv[2 * pi + 1];
        tile[r][c + 2 * pi]     = a * ce - bb * se;
        tile[r][c + 2 * pi + 1] = bb * ce + a * se;
    }
    __syncthreads();
    u16x4 o;
    o[0] = (ushort_t)f2bf(tile[c][r]);
    o[1] = (ushort_t)f2bf(tile[c + 1][r]);
    o[2] = (ushort_t)f2bf(tile[c + 2][r]);
    o[3] = (ushort_t)f2bf(tile[c + 3][r]);
    *(u16x4*)&kt2[((size_t)bh * 128 + kk0 + r) * T_SEQ + j0 + c] = o;
}

// ---------------------------------------------------------------------------
// Phase A: A_c[v][k] = sum_{j in chunk c} vt[v][j] * kt2[k][j]  (bf16 out)
// Block=(chunk, bh), 256 thr = 4 waves; wave w owns v-rows [64w,64w+64).
// No LDS, no barriers; operand fragments straight from global (L2).
// ---------------------------------------------------------------------------
__global__ __launch_bounds__(256)
void chunk_kv(const ushort_t* __restrict__ vt, const ushort_t* __restrict__ kt2,
              ushort_t* __restrict__ Abuf)
{
    const int c = blockIdx.x;
    const int bh = blockIdx.y;
    const int tid = threadIdx.x;
    const int w = tid >> 6, l = tid & 63, lc = l & 31, q = l >> 5;
    const int j0 = c * 64;

    f32x16 acc[2][4];
    #pragma unroll
    for (int mi = 0; mi < 2; ++mi)
        #pragma unroll
        for (int ni = 0; ni < 4; ++ni)
            #pragma unroll
            for (int e = 0; e < 16; ++e) acc[mi][ni][e] = 0.0f;

    #pragma unroll
    for (int ks = 0; ks < 4; ++ks) {
        bf16x8 a[2], bfr[4];
        #pragma unroll
        for (int mi = 0; mi < 2; ++mi)
            a[mi] = *(const bf16x8*)(vt + ((size_t)bh * 256 + w * 64 + mi * 32 + lc) * T_SEQ
                                     + j0 + ks * 16 + q * 8);
        #pragma unroll
        for (int ni = 0; ni < 4; ++ni)
            bfr[ni] = *(const bf16x8*)(kt2 + ((size_t)bh * 128 + ni * 32 + lc) * T_SEQ
                                       + j0 + ks * 16 + q * 8);
        #pragma unroll
        for (int mi = 0; mi < 2; ++mi)
            #pragma unroll
            for (int ni = 0; ni < 4; ++ni)
                acc[mi][ni] = __builtin_amdgcn_mfma_f32_32x32x16_bf16(
                    a[mi], bfr[ni], acc[mi][ni], 0, 0, 0);
    }

    ushort_t* ab = Abuf + (size_t)(bh * 32 + c) * 256 * 128;
    #pragma unroll
    for (int mi = 0; mi < 2; ++mi)
        #pragma unroll
        for (int ni = 0; ni < 4; ++ni)
            #pragma unroll
            for (int r = 0; r < 16; ++r) {
                const int v = w * 64 + mi * 32 + (r & 3) + 8 * (r >> 2) + 4 * q;
                const int k = ni * 32 + lc;
                ab[(size_t)v * 128 + k] = (ushort_t)f2bf(acc[mi][ni][r]);
            }
}

// ---------------------------------------------------------------------------
// Phase B: scan over chunks. St[c] = gamma * S_c (bf16, pre-mult for cross),
// S_{c+1} = g64*S_c + A_c.  Final state -> curr_kv (fp32).
// Thread = (bh, v, k), k fastest.
// ---------------------------------------------------------------------------
__global__ __launch_bounds__(256)
void scan_state(const ushort_t* __restrict__ Abuf, ushort_t* __restrict__ St,
                float* __restrict__ ckv)
{
    const int blk = blockIdx.x;            // bh*128 + sub
    const int bh = blk >> 7, sub = blk & 127;
    const int tid = threadIdx.x;
    const int v = sub * 2 + (tid >> 7), k = tid & 127;

    float ld, gamma;
    decay_params(bh & 7, ld, gamma);
    const float g64 = expf(ld * 64.0f);

    const size_t base = ((size_t)bh * 32 * 256 + v) * 128 + k;
    const size_t cstr = 256 * 128;
    float s = 0.0f;
    for (int c = 0; c < 32; ++c) {
        const size_t off = base + (size_t)c * cstr;
        St[off] = (ushort_t)f2bf(gamma * s);
        s = g64 * s + bf2f(Abuf[off]);
    }
    const float inv_scale = rsqrtf((1.0f - expf(ld * (float)T_SEQ)) / (1.0f - gamma));
    ckv[((size_t)bh * 128 + k) * 256 + v] = s * inv_scale;
}

// ---------------------------------------------------------------------------
// Phase C: per-i-tile output. 1024 single-wave blocks, zero LDS/barriers.
// O = masked intra-chunk retention + qh @ St[chunk]; fused groupnorm.
// qf serves as B-operand (intra K.Q^T) and A-operand (cross Q.S) — the
// 32x32x16 A/B register layouts are identical.
// ---------------------------------------------------------------------------
__global__ __launch_bounds__(64)
void retention_chunk(const ushort_t* __restrict__ qh,
                     const ushort_t* __restrict__ kh,
                     const ushort_t* __restrict__ vt,
                     const ushort_t* __restrict__ St,
                     float* __restrict__ normed)
{
    const int it = blockIdx.x;             // 0..63 i-tile
    const int bh = blockIdx.y;
    const int b = bh >> 3, h = bh & 7;
    const int c = it >> 1, w = it & 1;
    const int l = threadIdx.x, lc = l & 31, q = l >> 5;
    const int i0 = it * 32;
    const size_t bhT = (size_t)bh * T_SEQ;

    float ld, gamma;
    decay_params(h, ld, gamma);

    bf16x8 qf[8];
    {
        const ushort_t* qp = qh + (bhT + i0 + lc) * 128 + q * 8;
        #pragma unroll
        for (int c8 = 0; c8 < 8; ++c8)
            qf[c8] = *(const bf16x8*)(qp + c8 * 16);
    }

    f32x16 acc[8];
    #pragma unroll
    for (int vg = 0; vg < 8; ++vg)
        #pragma unroll
        for (int e = 0; e < 16; ++e) acc[vg][e] = 0.0f;

    // ---- cross-chunk: O += qh_i @ (gamma * S_c)  [St pre-multiplied] ----
    if (c > 0) {
        const ushort_t* sp = St + ((size_t)(bh * 32 + c) * 256 + lc) * 128 + q * 8;
        #pragma unroll
        for (int vg = 0; vg < 8; ++vg) {
            const ushort_t* spv = sp + (size_t)vg * 32 * 128;
            #pragma unroll
            for (int ks = 0; ks < 8; ++ks) {
                bf16x8 sb = *(const bf16x8*)(spv + ks * 16);
                acc[vg] = __builtin_amdgcn_mfma_f32_32x32x16_bf16(
                    qf[ks], sb, acc[vg], 0, 0, 0);
            }
        }
    }

    // ---- intra-chunk (mod-64 prescales make gamma^{i-j} exact; no csc) ----
    for (int jt2 = 0; jt2 <= w; ++jt2) {
        const int j0 = c * 64 + jt2 * 32;

        f32x16 s;
        #pragma unroll
        for (int e = 0; e < 16; ++e) s[e] = 0.0f;
        const ushort_t* kp = kh + (bhT + j0 + lc) * 128 + q * 8;
        #pragma unroll
        for (int c8 = 0; c8 < 8; ++c8) {
            bf16x8 ka = *(const bf16x8*)(kp + c8 * 16);
            s = __builtin_amdgcn_mfma_f32_32x32x16_bf16(ka, qf[c8], s, 0, 0, 0);
        }

        float sv[16];
        #pragma unroll
        for (int r = 0; r < 16; ++r) {
            float val = s[r];
            if (jt2 == w) {
                int jr_ = (r & 3) + 8 * (r >> 2) + 4 * q;
                val = (jr_ <= lc) ? val : 0.0f;
            }
            sv[r] = val;
        }

        bf16x8 pa0, pa1;
        #pragma unroll
        for (int e = 0; e < 4; ++e) {
            float t1 = __shfl_xor(sv[e + 4], 32);
            float t0 = __shfl_xor(sv[e], 32);
            pa0[e]     = f2bf(q ? t1 : sv[e]);
            pa0[e + 4] = f2bf(q ? sv[e + 4] : t0);
            float t3 = __shfl_xor(sv[e + 12], 32);
            float t2 = __shfl_xor(sv[e + 8], 32);
            pa1[e]     = f2bf(q ? t3 : sv[e + 8]);
            pa1[e + 4] = f2bf(q ? sv[e + 12] : t2);
        }

        #pragma unroll
        for (int vg = 0; vg < 8; ++vg) {
            const ushort_t* vp = vt + ((size_t)bh * 256 + vg * 32 + lc) * T_SEQ + j0 + q * 8;
            bf16x8 vb0 = *(const bf16x8*)vp;
            bf16x8 vb1 = *(const bf16x8*)(vp + 16);
            acc[vg] = __builtin_amdgcn_mfma_f32_32x32x16_bf16(pa0, vb0, acc[vg], 0, 0, 0);
            acc[vg] = __builtin_amdgcn_mfma_f32_32x32x16_bf16(pa1, vb1, acc[vg], 0, 0, 0);
        }
    }

    // ---- epilogue: row scale + fused groupnorm + store ----
    #pragma unroll
    for (int r = 0; r < 16; ++r) {
        const int il = (r & 3) + 8 * (r >> 2) + 4 * q;
        const int i  = i0 + il;
        float denom = (1.0f - expf(ld * (float)(i + 1))) / (1.0f - gamma);
        float fs = 0.08838834764831845f * rsqrtf(denom);
        float vals[8];
        float a1 = 0.0f, a2 = 0.0f;
        #pragma unroll
        for (int vg = 0; vg < 8; ++vg) {
            float x = acc[vg][r] * fs;
            vals[vg] = x;
            a1 += x; a2 += x * x;
        }
        a1 += __shfl_xor(a1, 1);  a2 += __shfl_xor(a2, 1);
        a1 += __shfl_xor(a1, 2);  a2 += __shfl_xor(a2, 2);
        a1 += __shfl_xor(a1, 4);  a2 += __shfl_xor(a2, 4);
        a1 += __shfl_xor(a1, 8);  a2 += __shfl_xor(a2, 8);
        a1 += __shfl_xor(a1, 16); a2 += __shfl_xor(a2, 16);
        float mu = a1 * (1.0f / 256.0f);
        float var = a2 * (1.0f / 256.0f) - mu * mu;
        float rs = rsqrtf(var + 1e-5f);
        float* op = normed + ((size_t)(b * T_SEQ + i)) * V_DIM + h * DV + lc;
        #pragma unroll
        for (int vg = 0; vg < 8; ++vg)
            op[vg * 32] = (vals[vg] - mu) * rs;
    }
}

// ---------------------------------------------------------------------------
extern "C" void kernel_launch(void* const* d_in, const int* in_sizes, int n_in,
                              void* d_out, int out_size, void* d_ws, size_t ws_size,
                              hipStream_t stream)
{
    const float* hs    = (const float*)d_in[0];
    const float* w_qkv = (const float*)d_in[1];
    const float* b_qkv = (const float*)d_in[2];
    const float* w_g   = (const float*)d_in[3];
    const float* b_g   = (const float*)d_in[4];
    const float* w_p   = (const float*)d_in[5];
    const float* b_p   = (const float*)d_in[6];
    float* out = (float*)d_out;

    const size_t MB = 1024 * 1024;
    // ws (96MB) timeline:
    //   [0,64)  fp32 qkv (live: gemm->preps)  -> Abuf [0,32) (A->scan) -> normed [0,32) (C->gated)
    //   [32,64) St (scan->C) -> gated_bf[32,48) + hs_bf2[48,56) + wg_t[56,60) + wp_t[60,64)
    //   [64,72) qh   [72,88) vt   [88,96) wqkv_t
    float*    qkv      = (float*)d_ws;
    ushort_t* Abuf     = (ushort_t*)d_ws;
    float*    normed   = (float*)d_ws;
    ushort_t* Stbuf    = (ushort_t*)((char*)d_ws + 32 * MB);
    ushort_t* gated_bf = (ushort_t*)((char*)d_ws + 32 * MB);
    ushort_t* hs_bf2   = (ushort_t*)((char*)d_ws + 48 * MB);
    ushort_t* wg_t     = (ushort_t*)((char*)d_ws + 56 * MB);
    ushort_t* wp_t     = (ushort_t*)((char*)d_ws + 60 * MB);
    ushort_t* qh       = (ushort_t*)((char*)d_ws + 64 * MB);
    ushort_t* vt       = (ushort_t*)((char*)d_ws + 72 * MB);
    ushort_t* wqkv_t   = (ushort_t*)((char*)d_ws + 88 * MB);
    // d_out scratch: hs_bf1 / kh at [0,8), kt2 at [8,16) — dead before proj store.
    ushort_t* hs_bf1   = (ushort_t*)d_out;
    ushort_t* kh       = (ushort_t*)d_out;
    ushort_t* kt2      = (ushort_t*)((char*)d_out + 8 * MB);
    float*    ckv_out  = out + (size_t)BT * E_DIM;

    // 1. conversions for qkv GEMM
    f32_to_bf16_kernel<<<dim3(2048), 256, 0, stream>>>(hs, hs_bf1);
    transpose_w_kernel<<<dim3(128, 32), 256, 0, stream>>>(w_qkv, wqkv_t, E_DIM, 4096);

    // 2. qkv = hs @ w_qkv + b_qkv (fp32)
    gemm_bf16<0><<<dim3(32, 32), 256, 0, stream>>>(
        hs_bf1, E_DIM, wqkv_t, E_DIM, b_qkv, qkv, QKV_LD, nullptr, 0, E_DIM / 32);

    // 3. preps (consume fp32 qkv)
    qk_prep<<<dim3(BT), 256, 0, stream>>>(qkv, qh, kh);
    v_transpose<<<dim3(64, 128), 256, 0, stream>>>(qkv, vt);
    kt2_prep<<<dim3(64, 64), 256, 0, stream>>>(qkv, kt2);

    // 4. chunked retention: A -> scan(S, curr_kv) -> outputs+groupnorm
    chunk_kv<<<dim3(32, 16), 256, 0, stream>>>(vt, kt2, Abuf);
    scan_state<<<dim3(2048), 256, 0, stream>>>(Abuf, Stbuf, ckv_out);
    retention_chunk<<<dim3(64, 16), 64, 0, stream>>>(qh, kh, vt, Stbuf, normed);

    // 5. late conversions (St/A regions free now)
    f32_to_bf16_kernel<<<dim3(2048), 256, 0, stream>>>(hs, hs_bf2);
    transpose_w_kernel<<<dim3(64, 32), 256, 0, stream>>>(w_g, wg_t, E_DIM, V_DIM);
    transpose_w_kernel<<<dim3(32, 64), 256, 0, stream>>>(w_p, wp_t, V_DIM, E_DIM);

    // 6. gated = silu(hs @ w_g + b_g) * normed -> bf16
    gemm_bf16<1><<<dim3(16, 32), 256, 0, stream>>>(
        hs_bf2, E_DIM, wg_t, E_DIM, b_g, gated_bf, V_DIM, normed, V_DIM, E_DIM / 32);

    // 7. proj = gated @ w_p + b_p (overwrites kh/kt2 scratch)
    gemm_bf16<0><<<dim3(8, 32), 256, 0, stream>>>(
        gated_bf, V_DIM, wp_t, V_DIM, b_p, out, E_DIM, nullptr, 0, V_DIM / 32);
}